// Round 1
// baseline (609.515 us; speedup 1.0000x reference)
//
#include <hip/hip_runtime.h>
#include <math.h>

typedef short short8 __attribute__((ext_vector_type(8)));
typedef float f32x4 __attribute__((ext_vector_type(4)));
typedef unsigned short u16;
typedef unsigned int u32;

#define GAS __attribute__((address_space(1)))
#define LAS __attribute__((address_space(3)))

static __device__ __forceinline__ u16 f2bf(float f) {
    union { float f; u32 u; } v; v.f = f;
    u32 r = v.u + 0x7FFFu + ((v.u >> 16) & 1u);
    return (u16)(r >> 16);
}

static __device__ __forceinline__ void gll16(const void* g, void* l) {
    __builtin_amdgcn_global_load_lds((const GAS void*)g, (LAS void*)l, 16, 0, 0);
}

// ---------- convert x rows to bf16 + row inverse norms (gs denominators) ----------
__global__ __launch_bounds__(256) void k_cvt_x(const float* __restrict__ x,
                                               u16* __restrict__ xb,
                                               float* __restrict__ xinv) {
    const int row = blockIdx.x, t = threadIdx.x;
    const f32x4 v = *(const f32x4*)(x + (size_t)row * 1024 + 4 * t);
    u32 w0 = (u32)f2bf(v.x) | ((u32)f2bf(v.y) << 16);
    u32 w1 = (u32)f2bf(v.z) | ((u32)f2bf(v.w) << 16);
    u32* dst = (u32*)(xb + (size_t)row * 1024 + 4 * t);
    dst[0] = w0; dst[1] = w1;
    float s = v.x * v.x + v.y * v.y + v.z * v.z + v.w * v.w;
#pragma unroll
    for (int off = 1; off < 64; off <<= 1) s += __shfl_xor(s, off, 64);
    __shared__ float red[4];
    if ((t & 63) == 0) red[t >> 6] = s;
    __syncthreads();
    if (t == 0)
        xinv[row] = 1.0f / fmaxf(sqrtf(red[0] + red[1] + red[2] + red[3]), 1e-12f);
}

// ---------- generic f32 -> bf16 convert (exact-size grids) ----------
__global__ __launch_bounds__(256) void k_cvt(const float* __restrict__ in,
                                             u16* __restrict__ out) {
    const size_t i = (size_t)blockIdx.x * 256 + threadIdx.x;
    const f32x4 v = *(const f32x4*)(in + 4 * i);
    u32 w0 = (u32)f2bf(v.x) | ((u32)f2bf(v.y) << 16);
    u32 w1 = (u32)f2bf(v.z) | ((u32)f2bf(v.w) << 16);
    u32* dst = (u32*)(out + 4 * i);
    dst[0] = w0; dst[1] = w1;
}

// ---------- GEMM1: wg_bf16[16384,1024] = x_bf @ W1_bf^T + b1 ; fused wg row-norm^2 atomics ----------
// m97-style 128x128 tile, BK=32, 4 waves (2x2), global_load_lds staging, 2 barriers/K-step.
__global__ __launch_bounds__(256) void k_gemm1(const u16* __restrict__ A,
                                               const u16* __restrict__ Bw,
                                               const float* __restrict__ bias,
                                               u16* __restrict__ C,
                                               float* __restrict__ wgn2) {
    __shared__ __align__(16) u16 lA[128 * 32];
    __shared__ __align__(16) u16 lB[128 * 32];
    const int K = 1024;
    const int m0 = blockIdx.y * 128, n0 = blockIdx.x * 128;
    const int tid = threadIdx.x, wave = tid >> 6, lane = tid & 63;
    const int wr = wave >> 1, wc = wave & 1;
    // staging: each 1KB chunk = 16 rows x 32 bf16; lane l -> row 16c + l/4, k-elem (l&3)*8
    const int srow = lane >> 2, ske = (lane & 3) * 8;
    const int c0 = wave * 2, c1 = wave * 2 + 1;
    const size_t a0 = (size_t)(m0 + 16 * c0 + srow) * K + ske;
    const size_t a1 = (size_t)(m0 + 16 * c1 + srow) * K + ske;
    const size_t b0 = (size_t)(n0 + 16 * c0 + srow) * K + ske;
    const size_t b1off = (size_t)(n0 + 16 * c1 + srow) * K + ske;
    const int lr = lane & 15, lk = (lane >> 4) * 8;
    f32x4 acc[4][4] = {};
    for (int kt = 0; kt < K; kt += 32) {
        gll16(A + a0 + kt, lA + c0 * 512);
        gll16(A + a1 + kt, lA + c1 * 512);
        gll16(Bw + b0 + kt, lB + c0 * 512);
        gll16(Bw + b1off + kt, lB + c1 * 512);
        __syncthreads();
        short8 af[4], bfr[4];
#pragma unroll
        for (int mf = 0; mf < 4; ++mf)
            af[mf] = *(const short8*)&lA[(wr * 64 + mf * 16 + lr) * 32 + lk];
#pragma unroll
        for (int nf = 0; nf < 4; ++nf)
            bfr[nf] = *(const short8*)&lB[(wc * 64 + nf * 16 + lr) * 32 + lk];
#pragma unroll
        for (int mf = 0; mf < 4; ++mf)
#pragma unroll
            for (int nf = 0; nf < 4; ++nf)
                acc[mf][nf] = __builtin_amdgcn_mfma_f32_16x16x32_bf16(af[mf], bfr[nf], acc[mf][nf], 0, 0, 0);
        __syncthreads();
    }
    const int col0 = n0 + wc * 64;
    const int row0 = m0 + wr * 64;
    float bcol[4];
#pragma unroll
    for (int nf = 0; nf < 4; ++nf) bcol[nf] = bias[col0 + nf * 16 + lr];
#pragma unroll
    for (int mf = 0; mf < 4; ++mf) {
#pragma unroll
        for (int r = 0; r < 4; ++r) {
            const int row = row0 + mf * 16 + (lane >> 4) * 4 + r;
            float nrm = 0.f;
#pragma unroll
            for (int nf = 0; nf < 4; ++nf) {
                float v = acc[mf][nf][r] + bcol[nf];
                C[(size_t)row * 1024 + col0 + nf * 16 + lr] = f2bf(v);
                nrm += v * v;
            }
#pragma unroll
            for (int off = 1; off < 16; off <<= 1) nrm += __shfl_xor(nrm, off, 64);
            if (lr == 0) atomicAdd(&wgn2[row], nrm);
        }
    }
}

// ---------- per-batch graph algebra: e_raw (MFMA), scores, softmax, e2, m copy ----------
__global__ __launch_bounds__(64) void k_batch(const u16* __restrict__ xb,
                                              const u16* __restrict__ wgb,
                                              const float* __restrict__ xinv,
                                              const float* __restrict__ wgn2,
                                              const float* __restrict__ matrix,
                                              const float* __restrict__ a_param,
                                              float* __restrict__ ascores,
                                              float* __restrict__ e2_out,
                                              float* __restrict__ m_out) {
    const int b = blockIdx.x, l = threadIdx.x;
    const int j = l & 15, ig = (l >> 4) * 4;
    // e_raw = x[b] @ wg[b]^T via 16x16x32 MFMA; fragments straight from global (L2-warm)
    const size_t roff = (size_t)(b * 16 + j) * 1024 + (l >> 4) * 8;
    f32x4 acc0 = {}, acc1 = {};
#pragma unroll
    for (int kt = 0; kt < 1024; kt += 64) {
        short8 xa0 = *(const short8*)(xb + roff + kt);
        short8 wa0 = *(const short8*)(wgb + roff + kt);
        short8 xa1 = *(const short8*)(xb + roff + kt + 32);
        short8 wa1 = *(const short8*)(wgb + roff + kt + 32);
        acc0 = __builtin_amdgcn_mfma_f32_16x16x32_bf16(xa0, wa0, acc0, 0, 0, 0);
        acc1 = __builtin_amdgcn_mfma_f32_16x16x32_bf16(xa1, wa1, acc1, 0, 0, 0);
    }
    // lane holds e for rows i = ig..ig+3, col j
    const float inw = 1.0f / fmaxf(sqrtf(wgn2[b * 16 + j]), 1e-12f);
    const float boost = 1.0f + a_param[0];
    float e[4];
#pragma unroll
    for (int r = 0; r < 4; ++r) {
        const int i = ig + r;
        float v = (acc0[r] + acc1[r]) * xinv[b * 16 + i] * inw;
        if (i == j) v *= boost;
        e[r] = v;
        ascores[(size_t)b * 256 + i * 16 + j] = v;   // pre-softmax (boosted) scores
    }
    // softmax over i (dim=1) within column j: lanes {j, j+16, j+32, j+48}
    float mx = fmaxf(fmaxf(e[0], e[1]), fmaxf(e[2], e[3]));
    mx = fmaxf(mx, __shfl_xor(mx, 16, 64));
    mx = fmaxf(mx, __shfl_xor(mx, 32, 64));
    float p[4], s = 0.f;
#pragma unroll
    for (int r = 0; r < 4; ++r) { p[r] = __expf(e[r] - mx); s += p[r]; }
    s += __shfl_xor(s, 16, 64);
    s += __shfl_xor(s, 32, 64);
    const float invs = 1.0f / s;

    __shared__ float esm_l[16 * 17];
    __shared__ float fi_l[16 * 17];
    __shared__ float e2_l[16 * 17];
    __shared__ float m_l[256];
#pragma unroll
    for (int r = 0; r < 4; ++r) esm_l[(ig + r) * 17 + j] = p[r] * invs;
    const f32x4 mv = *(const f32x4*)(matrix + (size_t)b * 256 + 4 * l);
    *(f32x4*)(m_l + 4 * l) = mv;
    *(f32x4*)(m_out + (size_t)b * 256 + 4 * l) = mv;   // output 3: m copy
    __syncthreads();
    // from_i[i][k] = sum_t esm[i][t] * m[t][k]  (lane: k=j, rows ig..ig+3)
    float fi[4] = {0, 0, 0, 0};
#pragma unroll
    for (int t = 0; t < 16; ++t) {
        const float mk = m_l[t * 16 + j];
#pragma unroll
        for (int r = 0; r < 4; ++r) fi[r] += esm_l[(ig + r) * 17 + t] * mk;
    }
#pragma unroll
    for (int r = 0; r < 4; ++r) fi_l[(ig + r) * 17 + j] = fi[r];
    __syncthreads();
    // e2[i][j] = sum_k from_i[i][k] * esm[j][k] * m[k][k]
    float e2v[4] = {0, 0, 0, 0};
#pragma unroll
    for (int kk = 0; kk < 16; ++kk) {
        const float w = esm_l[j * 17 + kk] * m_l[kk * 16 + kk];
#pragma unroll
        for (int r = 0; r < 4; ++r) e2v[r] += fi_l[(ig + r) * 17 + kk] * w;
    }
#pragma unroll
    for (int r = 0; r < 4; ++r) e2_l[(ig + r) * 17 + j] = e2v[r];
    __syncthreads();
#pragma unroll
    for (int r = 0; r < 4; ++r) {
        const int i = ig + r;
        e2_out[(size_t)b * 256 + i * 16 + j] = 0.5f * (e2_l[i * 17 + j] + e2_l[j * 17 + i]);
    }
}

// ---------- attn[b,i,f] = tanh(sum_j ascores[b,j,i] * x[b,j,f]) -> bf16 ----------
__global__ __launch_bounds__(256) void k_attn(const float* __restrict__ x,
                                              const float* __restrict__ ascores,
                                              u16* __restrict__ attn_bf) {
    __shared__ float xl[16][256];
    __shared__ float as_l[256];
    const int b = blockIdx.y, f0 = blockIdx.x * 256, t = threadIdx.x;
    as_l[t] = ascores[(size_t)b * 256 + t];
#pragma unroll
    for (int jj = 0; jj < 16; ++jj)
        xl[jj][t] = x[((size_t)b * 16 + jj) * 1024 + f0 + t];
    __syncthreads();
    float accv[16] = {};
#pragma unroll
    for (int jj = 0; jj < 16; ++jj) {
        const float xv = xl[jj][t];
#pragma unroll
        for (int i = 0; i < 16; ++i) accv[i] = fmaf(as_l[jj * 16 + i], xv, accv[i]);
    }
#pragma unroll
    for (int i = 0; i < 16; ++i)
        attn_bf[((size_t)b * 16 + i) * 1024 + f0 + t] = f2bf(tanhf(accv[i]));
}

// ---------- GEMM2: out_partial[z][1024,4096] = attn_bf @ W_mlp_bf^T (split-K=2) ----------
__global__ __launch_bounds__(256) void k_gemm2(const u16* __restrict__ A,
                                               const u16* __restrict__ Bw,
                                               float* __restrict__ outp) {
    __shared__ __align__(16) u16 lA[128 * 32];
    __shared__ __align__(16) u16 lB[128 * 32];
    const int K = 16384;
    const int n0 = blockIdx.x * 128, m0 = blockIdx.y * 128;
    const int kbeg = blockIdx.z * 8192, kend = kbeg + 8192;
    const int tid = threadIdx.x, wave = tid >> 6, lane = tid & 63;
    const int wr = wave >> 1, wc = wave & 1;
    const int srow = lane >> 2, ske = (lane & 3) * 8;
    const int c0 = wave * 2, c1 = wave * 2 + 1;
    const size_t a0 = (size_t)(m0 + 16 * c0 + srow) * K + ske;
    const size_t a1 = (size_t)(m0 + 16 * c1 + srow) * K + ske;
    const size_t b0 = (size_t)(n0 + 16 * c0 + srow) * K + ske;
    const size_t b1off = (size_t)(n0 + 16 * c1 + srow) * K + ske;
    const int lr = lane & 15, lk = (lane >> 4) * 8;
    f32x4 acc[4][4] = {};
    for (int kt = kbeg; kt < kend; kt += 32) {
        gll16(A + a0 + kt, lA + c0 * 512);
        gll16(A + a1 + kt, lA + c1 * 512);
        gll16(Bw + b0 + kt, lB + c0 * 512);
        gll16(Bw + b1off + kt, lB + c1 * 512);
        __syncthreads();
        short8 af[4], bfr[4];
#pragma unroll
        for (int mf = 0; mf < 4; ++mf)
            af[mf] = *(const short8*)&lA[(wr * 64 + mf * 16 + lr) * 32 + lk];
#pragma unroll
        for (int nf = 0; nf < 4; ++nf)
            bfr[nf] = *(const short8*)&lB[(wc * 64 + nf * 16 + lr) * 32 + lk];
#pragma unroll
        for (int mf = 0; mf < 4; ++mf)
#pragma unroll
            for (int nf = 0; nf < 4; ++nf)
                acc[mf][nf] = __builtin_amdgcn_mfma_f32_16x16x32_bf16(af[mf], bfr[nf], acc[mf][nf], 0, 0, 0);
        __syncthreads();
    }
    float* po = outp + (size_t)blockIdx.z * 1024 * 4096;
    const int col0 = n0 + wc * 64;
    const int row0 = m0 + wr * 64;
#pragma unroll
    for (int mf = 0; mf < 4; ++mf)
#pragma unroll
        for (int r = 0; r < 4; ++r) {
            const int row = row0 + mf * 16 + (lane >> 4) * 4 + r;
#pragma unroll
            for (int nf = 0; nf < 4; ++nf)
                po[(size_t)row * 4096 + col0 + nf * 16 + lr] = acc[mf][nf][r];
        }
}

// ---------- broadcast: out[b, rep, :] = p0[b,:] + p1[b,:] + b_mlp ----------
__global__ __launch_bounds__(256) void k_bcast(const float* __restrict__ p0,
                                               const float* __restrict__ p1,
                                               const float* __restrict__ bias,
                                               float* __restrict__ out) {
    const size_t i = (size_t)blockIdx.x * 256 + threadIdx.x;  // over 16,777,216 float4
    const int o4 = (int)(i & 1023);
    const int b = (int)(i >> 14);
    const size_t src = ((size_t)b * 1024 + o4) * 4;
    const f32x4 v0 = *(const f32x4*)(p0 + src);
    const f32x4 v1 = *(const f32x4*)(p1 + src);
    const f32x4 bb = *(const f32x4*)(bias + (size_t)o4 * 4);
    const f32x4 r = v0 + v1 + bb;
    *(f32x4*)(out + i * 4) = r;
}

extern "C" void kernel_launch(void* const* d_in, const int* in_sizes, int n_in,
                              void* d_out, int out_size, void* d_ws, size_t ws_size,
                              hipStream_t stream) {
    const float* x      = (const float*)d_in[0];
    const float* matrix = (const float*)d_in[1];
    const float* W1     = (const float*)d_in[2];
    const float* b1     = (const float*)d_in[3];
    const float* W_mlp  = (const float*)d_in[4];
    const float* b_mlp  = (const float*)d_in[5];
    const float* a_par  = (const float*)d_in[6];
    float* out = (float*)d_out;

    char* ws = (char*)d_ws;
    size_t off = 0;
    auto alloc = [&](size_t bytes) {
        char* p = ws + off;
        off += (bytes + 255) & ~(size_t)255;
        return p;
    };
    u16*   x_bf  = (u16*)alloc(16384ull * 1024 * 2);    // reused as attn_bf after k_batch
    u16*   wg_bf = (u16*)alloc(16384ull * 1024 * 2);    // reused as GEMM2 partials after k_batch
    u16*   w1_bf = (u16*)alloc(1024ull * 1024 * 2);
    u16*   wm_bf = (u16*)alloc(4096ull * 16384 * 2);
    float* xinv  = (float*)alloc(16384ull * 4);
    float* wgn2  = (float*)alloc(16384ull * 4);
    float* ascr  = (float*)alloc(1024ull * 256 * 4);
    u16*   attn_bf = x_bf;
    float* outp    = (float*)wg_bf;                      // 2 x 16MB fits exactly in 32MB
    float* e2_out = out + 67108864ull;
    float* m_out  = out + 67371008ull;

    hipMemsetAsync(wgn2, 0, 16384 * 4, stream);
    k_cvt_x<<<16384, 256, 0, stream>>>(x, x_bf, xinv);
    k_cvt<<<1024, 256, 0, stream>>>(W1, w1_bf);                  // 1M elems
    k_cvt<<<65536, 256, 0, stream>>>(W_mlp, wm_bf);              // 67M elems
    k_gemm1<<<dim3(8, 128), 256, 0, stream>>>(x_bf, w1_bf, b1, wg_bf, wgn2);
    k_batch<<<1024, 64, 0, stream>>>(x_bf, wg_bf, xinv, wgn2, matrix, a_par,
                                     ascr, e2_out, m_out);
    k_attn<<<dim3(4, 1024), 256, 0, stream>>>(x, ascr, attn_bf);
    k_gemm2<<<dim3(32, 8, 2), 256, 0, stream>>>(attn_bf, wm_bf, outp);
    k_bcast<<<65536, 256, 0, stream>>>(outp, outp + 1024ull * 4096, b_mlp, out);
}

// Round 2
// 607.617 us; speedup vs baseline: 1.0031x; 1.0031x over previous
//
#include <hip/hip_runtime.h>
#include <math.h>

typedef short short8 __attribute__((ext_vector_type(8)));
typedef float f32x4 __attribute__((ext_vector_type(4)));
typedef unsigned short u16;
typedef unsigned int u32;

#define GAS __attribute__((address_space(1)))
#define LAS __attribute__((address_space(3)))

static __device__ __forceinline__ u16 f2bf(float f) {
    union { float f; u32 u; } v; v.f = f;
    u32 r = v.u + 0x7FFFu + ((v.u >> 16) & 1u);
    return (u16)(r >> 16);
}

static __device__ __forceinline__ void gll16(const void* g, void* l) {
    __builtin_amdgcn_global_load_lds((const GAS void*)g, (LAS void*)l, 16, 0, 0);
}

// ---------- convert x rows to bf16 + row inverse norms (gs denominators) ----------
__global__ __launch_bounds__(256) void k_cvt_x(const float* __restrict__ x,
                                               u16* __restrict__ xb,
                                               float* __restrict__ xinv) {
    const int row = blockIdx.x, t = threadIdx.x;
    const f32x4 v = *(const f32x4*)(x + (size_t)row * 1024 + 4 * t);
    u32 w0 = (u32)f2bf(v.x) | ((u32)f2bf(v.y) << 16);
    u32 w1 = (u32)f2bf(v.z) | ((u32)f2bf(v.w) << 16);
    u32* dst = (u32*)(xb + (size_t)row * 1024 + 4 * t);
    dst[0] = w0; dst[1] = w1;
    float s = v.x * v.x + v.y * v.y + v.z * v.z + v.w * v.w;
#pragma unroll
    for (int off = 1; off < 64; off <<= 1) s += __shfl_xor(s, off, 64);
    __shared__ float red[4];
    if ((t & 63) == 0) red[t >> 6] = s;
    __syncthreads();
    if (t == 0)
        xinv[row] = 1.0f / fmaxf(sqrtf(red[0] + red[1] + red[2] + red[3]), 1e-12f);
}

// ---------- generic f32 -> bf16 convert ----------
__global__ __launch_bounds__(256) void k_cvt(const float* __restrict__ in,
                                             u16* __restrict__ out) {
    const size_t i = (size_t)blockIdx.x * 256 + threadIdx.x;
    const f32x4 v = *(const f32x4*)(in + 4 * i);
    u32 w0 = (u32)f2bf(v.x) | ((u32)f2bf(v.y) << 16);
    u32 w1 = (u32)f2bf(v.z) | ((u32)f2bf(v.w) << 16);
    u32* dst = (u32*)(out + 4 * i);
    dst[0] = w0; dst[1] = w1;
}

// ---------- GEMM1: wg_bf16[16384,1024] = x_bf @ W1_bf^T + b1 ; fused wg row-norm^2 ----------
// 128x128 tile, BK=32, 4 waves, double-buffered LDS (T3-min), 1 barrier/K-step, XCD swizzle.
__global__ __launch_bounds__(256) void k_gemm1(const u16* __restrict__ A,
                                               const u16* __restrict__ Bw,
                                               const float* __restrict__ bias,
                                               u16* __restrict__ C,
                                               float* __restrict__ wgn2) {
    __shared__ __align__(16) u16 lA[2][128 * 32];
    __shared__ __align__(16) u16 lB[2][128 * 32];
    const int K = 1024;
    // bijective XCD swizzle, nwg=1024 (8 XCDs x 128): n fastest (A-panel reuse, W1 L2-fits)
    const int lin = blockIdx.x;
    const int w = (lin & 7) * 128 + (lin >> 3);
    const int n0 = (w & 7) * 128, m0 = (w >> 3) * 128;
    const int tid = threadIdx.x, wave = tid >> 6, lane = tid & 63;
    const int wr = wave >> 1, wc = wave & 1;
    const int srow = lane >> 2, ske = (lane & 3) * 8;
    const int c0 = wave * 2, c1 = wave * 2 + 1;
    const size_t a0 = (size_t)(m0 + 16 * c0 + srow) * K + ske;
    const size_t a1 = (size_t)(m0 + 16 * c1 + srow) * K + ske;
    const size_t b0 = (size_t)(n0 + 16 * c0 + srow) * K + ske;
    const size_t b1o = (size_t)(n0 + 16 * c1 + srow) * K + ske;
    const int lr = lane & 15, lk = (lane >> 4) * 8;
    f32x4 acc[4][4] = {};
    // prologue
    gll16(A + a0, lA[0] + c0 * 512);
    gll16(A + a1, lA[0] + c1 * 512);
    gll16(Bw + b0, lB[0] + c0 * 512);
    gll16(Bw + b1o, lB[0] + c1 * 512);
    __syncthreads();
    int cur = 0;
    for (int kt = 0; kt < K; kt += 32) {
        const int nxt = kt + 32;
        if (nxt < K) {
            gll16(A + a0 + nxt, lA[cur ^ 1] + c0 * 512);
            gll16(A + a1 + nxt, lA[cur ^ 1] + c1 * 512);
            gll16(Bw + b0 + nxt, lB[cur ^ 1] + c0 * 512);
            gll16(Bw + b1o + nxt, lB[cur ^ 1] + c1 * 512);
        }
        short8 af[4], bfr[4];
#pragma unroll
        for (int mf = 0; mf < 4; ++mf)
            af[mf] = *(const short8*)&lA[cur][(wr * 64 + mf * 16 + lr) * 32 + lk];
#pragma unroll
        for (int nf = 0; nf < 4; ++nf)
            bfr[nf] = *(const short8*)&lB[cur][(wc * 64 + nf * 16 + lr) * 32 + lk];
#pragma unroll
        for (int mf = 0; mf < 4; ++mf)
#pragma unroll
            for (int nf = 0; nf < 4; ++nf)
                acc[mf][nf] = __builtin_amdgcn_mfma_f32_16x16x32_bf16(af[mf], bfr[nf], acc[mf][nf], 0, 0, 0);
        __syncthreads();
        cur ^= 1;
    }
    const int col0 = n0 + wc * 64;
    const int row0 = m0 + wr * 64;
    float bcol[4];
#pragma unroll
    for (int nf = 0; nf < 4; ++nf) bcol[nf] = bias[col0 + nf * 16 + lr];
#pragma unroll
    for (int mf = 0; mf < 4; ++mf) {
#pragma unroll
        for (int r = 0; r < 4; ++r) {
            const int row = row0 + mf * 16 + (lane >> 4) * 4 + r;
            float nrm = 0.f;
#pragma unroll
            for (int nf = 0; nf < 4; ++nf) {
                float v = acc[mf][nf][r] + bcol[nf];
                C[(size_t)row * 1024 + col0 + nf * 16 + lr] = f2bf(v);
                nrm += v * v;
            }
#pragma unroll
            for (int off = 1; off < 16; off <<= 1) nrm += __shfl_xor(nrm, off, 64);
            if (lr == 0) atomicAdd(&wgn2[row], nrm);
        }
    }
}

// ---------- per-batch graph algebra ----------
__global__ __launch_bounds__(64) void k_batch(const u16* __restrict__ xb,
                                              const u16* __restrict__ wgb,
                                              const float* __restrict__ xinv,
                                              const float* __restrict__ wgn2,
                                              const float* __restrict__ matrix,
                                              const float* __restrict__ a_param,
                                              float* __restrict__ ascores,
                                              float* __restrict__ e2_out,
                                              float* __restrict__ m_out) {
    const int b = blockIdx.x, l = threadIdx.x;
    const int j = l & 15, ig = (l >> 4) * 4;
    const size_t roff = (size_t)(b * 16 + j) * 1024 + (l >> 4) * 8;
    f32x4 acc0 = {}, acc1 = {};
#pragma unroll
    for (int kt = 0; kt < 1024; kt += 64) {
        short8 xa0 = *(const short8*)(xb + roff + kt);
        short8 wa0 = *(const short8*)(wgb + roff + kt);
        short8 xa1 = *(const short8*)(xb + roff + kt + 32);
        short8 wa1 = *(const short8*)(wgb + roff + kt + 32);
        acc0 = __builtin_amdgcn_mfma_f32_16x16x32_bf16(xa0, wa0, acc0, 0, 0, 0);
        acc1 = __builtin_amdgcn_mfma_f32_16x16x32_bf16(xa1, wa1, acc1, 0, 0, 0);
    }
    const float inw = 1.0f / fmaxf(sqrtf(wgn2[b * 16 + j]), 1e-12f);
    const float boost = 1.0f + a_param[0];
    float e[4];
#pragma unroll
    for (int r = 0; r < 4; ++r) {
        const int i = ig + r;
        float v = (acc0[r] + acc1[r]) * xinv[b * 16 + i] * inw;
        if (i == j) v *= boost;
        e[r] = v;
        ascores[(size_t)b * 256 + i * 16 + j] = v;
    }
    float mx = fmaxf(fmaxf(e[0], e[1]), fmaxf(e[2], e[3]));
    mx = fmaxf(mx, __shfl_xor(mx, 16, 64));
    mx = fmaxf(mx, __shfl_xor(mx, 32, 64));
    float p[4], s = 0.f;
#pragma unroll
    for (int r = 0; r < 4; ++r) { p[r] = __expf(e[r] - mx); s += p[r]; }
    s += __shfl_xor(s, 16, 64);
    s += __shfl_xor(s, 32, 64);
    const float invs = 1.0f / s;

    __shared__ float esm_l[16 * 17];
    __shared__ float fi_l[16 * 17];
    __shared__ float e2_l[16 * 17];
    __shared__ float m_l[256];
#pragma unroll
    for (int r = 0; r < 4; ++r) esm_l[(ig + r) * 17 + j] = p[r] * invs;
    const f32x4 mv = *(const f32x4*)(matrix + (size_t)b * 256 + 4 * l);
    *(f32x4*)(m_l + 4 * l) = mv;
    *(f32x4*)(m_out + (size_t)b * 256 + 4 * l) = mv;
    __syncthreads();
    float fi[4] = {0, 0, 0, 0};
#pragma unroll
    for (int t = 0; t < 16; ++t) {
        const float mk = m_l[t * 16 + j];
#pragma unroll
        for (int r = 0; r < 4; ++r) fi[r] += esm_l[(ig + r) * 17 + t] * mk;
    }
#pragma unroll
    for (int r = 0; r < 4; ++r) fi_l[(ig + r) * 17 + j] = fi[r];
    __syncthreads();
    float e2v[4] = {0, 0, 0, 0};
#pragma unroll
    for (int kk = 0; kk < 16; ++kk) {
        const float w = esm_l[j * 17 + kk] * m_l[kk * 16 + kk];
#pragma unroll
        for (int r = 0; r < 4; ++r) e2v[r] += fi_l[(ig + r) * 17 + kk] * w;
    }
#pragma unroll
    for (int r = 0; r < 4; ++r) e2_l[(ig + r) * 17 + j] = e2v[r];
    __syncthreads();
#pragma unroll
    for (int r = 0; r < 4; ++r) {
        const int i = ig + r;
        e2_out[(size_t)b * 256 + i * 16 + j] = 0.5f * (e2_l[i * 17 + j] + e2_l[j * 17 + i]);
    }
}

// ---------- attn[b,i,f] = tanh(sum_j ascores[b,j,i] * x[b,j,f]) -> bf16 ----------
__global__ __launch_bounds__(256) void k_attn(const float* __restrict__ x,
                                              const float* __restrict__ ascores,
                                              u16* __restrict__ attn_bf) {
    __shared__ float xl[16][256];
    __shared__ float as_l[256];
    const int b = blockIdx.y, f0 = blockIdx.x * 256, t = threadIdx.x;
    as_l[t] = ascores[(size_t)b * 256 + t];
#pragma unroll
    for (int jj = 0; jj < 16; ++jj)
        xl[jj][t] = x[((size_t)b * 16 + jj) * 1024 + f0 + t];
    __syncthreads();
    float accv[16] = {};
#pragma unroll
    for (int jj = 0; jj < 16; ++jj) {
        const float xv = xl[jj][t];
#pragma unroll
        for (int i = 0; i < 16; ++i) accv[i] = fmaf(as_l[jj * 16 + i], xv, accv[i]);
    }
#pragma unroll
    for (int i = 0; i < 16; ++i)
        attn_bf[((size_t)b * 16 + i) * 1024 + f0 + t] = f2bf(tanhf(accv[i]));
}

// ---------- GEMM2: outp[1024,4096] += attn_bf @ W_mlp_bf^T (split-K=4, atomic merge) ----------
// 128x128, BK=32, dbuf LDS, 1 barrier/K-step, XCD swizzle with m-fastest decode (B-panel L2 reuse)
__global__ __launch_bounds__(256) void k_gemm2(const u16* __restrict__ A,
                                               const u16* __restrict__ Bw,
                                               float* __restrict__ outp) {
    __shared__ __align__(16) u16 lA[2][128 * 32];
    __shared__ __align__(16) u16 lB[2][128 * 32];
    const int K = 16384;
    // nwg = 1024 = 8 m x 32 n x 4 z ; swizzle then decode m fastest
    const int lin = blockIdx.x;
    const int w = (lin & 7) * 128 + (lin >> 3);
    const int m0 = (w & 7) * 128;
    const int n0 = ((w >> 3) & 31) * 128;
    const int kbeg = (w >> 8) * 4096, kend = kbeg + 4096;
    const int tid = threadIdx.x, wave = tid >> 6, lane = tid & 63;
    const int wr = wave >> 1, wc = wave & 1;
    const int srow = lane >> 2, ske = (lane & 3) * 8;
    const int c0 = wave * 2, c1 = wave * 2 + 1;
    const size_t a0 = (size_t)(m0 + 16 * c0 + srow) * K + ske;
    const size_t a1 = (size_t)(m0 + 16 * c1 + srow) * K + ske;
    const size_t b0 = (size_t)(n0 + 16 * c0 + srow) * K + ske;
    const size_t b1o = (size_t)(n0 + 16 * c1 + srow) * K + ske;
    const int lr = lane & 15, lk = (lane >> 4) * 8;
    f32x4 acc[4][4] = {};
    gll16(A + a0 + kbeg, lA[0] + c0 * 512);
    gll16(A + a1 + kbeg, lA[0] + c1 * 512);
    gll16(Bw + b0 + kbeg, lB[0] + c0 * 512);
    gll16(Bw + b1o + kbeg, lB[0] + c1 * 512);
    __syncthreads();
    int cur = 0;
    for (int kt = kbeg; kt < kend; kt += 32) {
        const int nxt = kt + 32;
        if (nxt < kend) {
            gll16(A + a0 + nxt, lA[cur ^ 1] + c0 * 512);
            gll16(A + a1 + nxt, lA[cur ^ 1] + c1 * 512);
            gll16(Bw + b0 + nxt, lB[cur ^ 1] + c0 * 512);
            gll16(Bw + b1o + nxt, lB[cur ^ 1] + c1 * 512);
        }
        short8 af[4], bfr[4];
#pragma unroll
        for (int mf = 0; mf < 4; ++mf)
            af[mf] = *(const short8*)&lA[cur][(wr * 64 + mf * 16 + lr) * 32 + lk];
#pragma unroll
        for (int nf = 0; nf < 4; ++nf)
            bfr[nf] = *(const short8*)&lB[cur][(wc * 64 + nf * 16 + lr) * 32 + lk];
#pragma unroll
        for (int mf = 0; mf < 4; ++mf)
#pragma unroll
            for (int nf = 0; nf < 4; ++nf)
                acc[mf][nf] = __builtin_amdgcn_mfma_f32_16x16x32_bf16(af[mf], bfr[nf], acc[mf][nf], 0, 0, 0);
        __syncthreads();
        cur ^= 1;
    }
    const int col0 = n0 + wc * 64;
    const int row0 = m0 + wr * 64;
#pragma unroll
    for (int mf = 0; mf < 4; ++mf)
#pragma unroll
        for (int r = 0; r < 4; ++r) {
            const int row = row0 + mf * 16 + (lane >> 4) * 4 + r;
#pragma unroll
            for (int nf = 0; nf < 4; ++nf)
                atomicAdd(&outp[(size_t)row * 4096 + col0 + nf * 16 + lr], acc[mf][nf][r]);
        }
}

// ---------- broadcast: out[b, rep, :] = p[b,:] + b_mlp ----------
__global__ __launch_bounds__(256) void k_bcast(const float* __restrict__ p0,
                                               const float* __restrict__ bias,
                                               float* __restrict__ out) {
    const size_t i = (size_t)blockIdx.x * 256 + threadIdx.x;  // 16,777,216 float4
    const int o4 = (int)(i & 1023);
    const int b = (int)(i >> 14);
    const f32x4 v0 = *(const f32x4*)(p0 + ((size_t)b * 1024 + o4) * 4);
    const f32x4 bb = *(const f32x4*)(bias + (size_t)o4 * 4);
    const f32x4 r = v0 + bb;
    *(f32x4*)(out + i * 4) = r;
}

extern "C" void kernel_launch(void* const* d_in, const int* in_sizes, int n_in,
                              void* d_out, int out_size, void* d_ws, size_t ws_size,
                              hipStream_t stream) {
    const float* x      = (const float*)d_in[0];
    const float* matrix = (const float*)d_in[1];
    const float* W1     = (const float*)d_in[2];
    const float* b1     = (const float*)d_in[3];
    const float* W_mlp  = (const float*)d_in[4];
    const float* b_mlp  = (const float*)d_in[5];
    const float* a_par  = (const float*)d_in[6];
    float* out = (float*)d_out;

    char* ws = (char*)d_ws;
    size_t off = 0;
    auto alloc = [&](size_t bytes) {
        char* p = ws + off;
        off += (bytes + 255) & ~(size_t)255;
        return p;
    };
    u16*   x_bf  = (u16*)alloc(16384ull * 1024 * 2);    // reused as attn_bf after k_batch
    u16*   wg_bf = (u16*)alloc(16384ull * 1024 * 2);    // reused as GEMM2 partial after k_batch
    u16*   w1_bf = (u16*)alloc(1024ull * 1024 * 2);
    u16*   wm_bf = (u16*)alloc(4096ull * 16384 * 2);
    float* xinv  = (float*)alloc(16384ull * 4);
    float* wgn2  = (float*)alloc(16384ull * 4);
    float* ascr  = (float*)alloc(1024ull * 256 * 4);
    u16*   attn_bf = x_bf;
    float* outp    = (float*)wg_bf;                      // 16MB partial (wg_bf dead by then)
    float* e2_out = out + 67108864ull;
    float* m_out  = out + 67371008ull;

    hipMemsetAsync(wgn2, 0, 16384 * 4, stream);
    k_cvt_x<<<16384, 256, 0, stream>>>(x, x_bf, xinv);
    k_cvt<<<1024, 256, 0, stream>>>(W1, w1_bf);
    k_cvt<<<65536, 256, 0, stream>>>(W_mlp, wm_bf);
    k_gemm1<<<1024, 256, 0, stream>>>(x_bf, w1_bf, b1, wg_bf, wgn2);
    k_batch<<<1024, 64, 0, stream>>>(x_bf, wg_bf, xinv, wgn2, matrix, a_par,
                                     ascr, e2_out, m_out);
    k_attn<<<dim3(4, 1024), 256, 0, stream>>>(x, ascr, attn_bf);
    hipMemsetAsync(outp, 0, 1024ull * 4096 * 4, stream);
    k_gemm2<<<1024, 256, 0, stream>>>(attn_bf, wm_bf, outp);
    k_bcast<<<65536, 256, 0, stream>>>(outp, b_mlp, out);
}

// Round 3
// 499.327 us; speedup vs baseline: 1.2207x; 1.2169x over previous
//
#include <hip/hip_runtime.h>
#include <math.h>

typedef short short8 __attribute__((ext_vector_type(8)));
typedef float f32x4 __attribute__((ext_vector_type(4)));
typedef unsigned short us4 __attribute__((ext_vector_type(4)));
typedef unsigned short u16;
typedef unsigned int u32;

#define GAS __attribute__((address_space(1)))
#define LAS __attribute__((address_space(3)))

static __device__ __forceinline__ u16 f2bf(float f) {
    union { float f; u32 u; } v; v.f = f;
    u32 r = v.u + 0x7FFFu + ((v.u >> 16) & 1u);
    return (u16)(r >> 16);
}

static __device__ __forceinline__ float bf2f(u16 h) {
    union { u32 u; float f; } v; v.u = ((u32)h) << 16;
    return v.f;
}

static __device__ __forceinline__ void gll16(const void* g, void* l) {
    __builtin_amdgcn_global_load_lds((const GAS void*)g, (LAS void*)l, 16, 0, 0);
}

// ---------- convert x rows to bf16 + row inverse norms ----------
__global__ __launch_bounds__(256) void k_cvt_x(const float* __restrict__ x,
                                               u16* __restrict__ xb,
                                               float* __restrict__ xinv) {
    const int row = blockIdx.x, t = threadIdx.x;
    const f32x4 v = *(const f32x4*)(x + (size_t)row * 1024 + 4 * t);
    u32 w0 = (u32)f2bf(v.x) | ((u32)f2bf(v.y) << 16);
    u32 w1 = (u32)f2bf(v.z) | ((u32)f2bf(v.w) << 16);
    u32* dst = (u32*)(xb + (size_t)row * 1024 + 4 * t);
    dst[0] = w0; dst[1] = w1;
    float s = v.x * v.x + v.y * v.y + v.z * v.z + v.w * v.w;
#pragma unroll
    for (int off = 1; off < 64; off <<= 1) s += __shfl_xor(s, off, 64);
    __shared__ float red[4];
    if ((t & 63) == 0) red[t >> 6] = s;
    __syncthreads();
    if (t == 0)
        xinv[row] = 1.0f / fmaxf(sqrtf(red[0] + red[1] + red[2] + red[3]), 1e-12f);
}

// ---------- generic f32 -> bf16 convert ----------
__global__ __launch_bounds__(256) void k_cvt(const float* __restrict__ in,
                                             u16* __restrict__ out) {
    const size_t i = (size_t)blockIdx.x * 256 + threadIdx.x;
    const f32x4 v = *(const f32x4*)(in + 4 * i);
    u32 w0 = (u32)f2bf(v.x) | ((u32)f2bf(v.y) << 16);
    u32 w1 = (u32)f2bf(v.z) | ((u32)f2bf(v.w) << 16);
    u32* dst = (u32*)(out + 4 * i);
    dst[0] = w0; dst[1] = w1;
}

// ---------- GEMM1: wg_bf16 = x_bf @ W1_bf^T + b1 ; fused row-norm^2 (unchanged, works) ----------
__global__ __launch_bounds__(256) void k_gemm1(const u16* __restrict__ A,
                                               const u16* __restrict__ Bw,
                                               const float* __restrict__ bias,
                                               u16* __restrict__ C,
                                               float* __restrict__ wgn2) {
    __shared__ __align__(16) u16 lA[2][128 * 32];
    __shared__ __align__(16) u16 lB[2][128 * 32];
    const int K = 1024;
    const int lin = blockIdx.x;
    const int w = (lin & 7) * 128 + (lin >> 3);
    const int n0 = (w & 7) * 128, m0 = (w >> 3) * 128;
    const int tid = threadIdx.x, wave = tid >> 6, lane = tid & 63;
    const int wr = wave >> 1, wc = wave & 1;
    const int srow = lane >> 2, ske = (lane & 3) * 8;
    const int c0 = wave * 2, c1 = wave * 2 + 1;
    const size_t a0 = (size_t)(m0 + 16 * c0 + srow) * K + ske;
    const size_t a1 = (size_t)(m0 + 16 * c1 + srow) * K + ske;
    const size_t b0 = (size_t)(n0 + 16 * c0 + srow) * K + ske;
    const size_t b1o = (size_t)(n0 + 16 * c1 + srow) * K + ske;
    const int lr = lane & 15, lk = (lane >> 4) * 8;
    f32x4 acc[4][4] = {};
    gll16(A + a0, lA[0] + c0 * 512);
    gll16(A + a1, lA[0] + c1 * 512);
    gll16(Bw + b0, lB[0] + c0 * 512);
    gll16(Bw + b1o, lB[0] + c1 * 512);
    __syncthreads();
    int cur = 0;
    for (int kt = 0; kt < K; kt += 32) {
        const int nxt = kt + 32;
        if (nxt < K) {
            gll16(A + a0 + nxt, lA[cur ^ 1] + c0 * 512);
            gll16(A + a1 + nxt, lA[cur ^ 1] + c1 * 512);
            gll16(Bw + b0 + nxt, lB[cur ^ 1] + c0 * 512);
            gll16(Bw + b1o + nxt, lB[cur ^ 1] + c1 * 512);
        }
        short8 af[4], bfr[4];
#pragma unroll
        for (int mf = 0; mf < 4; ++mf)
            af[mf] = *(const short8*)&lA[cur][(wr * 64 + mf * 16 + lr) * 32 + lk];
#pragma unroll
        for (int nf = 0; nf < 4; ++nf)
            bfr[nf] = *(const short8*)&lB[cur][(wc * 64 + nf * 16 + lr) * 32 + lk];
#pragma unroll
        for (int mf = 0; mf < 4; ++mf)
#pragma unroll
            for (int nf = 0; nf < 4; ++nf)
                acc[mf][nf] = __builtin_amdgcn_mfma_f32_16x16x32_bf16(af[mf], bfr[nf], acc[mf][nf], 0, 0, 0);
        __syncthreads();
        cur ^= 1;
    }
    const int col0 = n0 + wc * 64;
    const int row0 = m0 + wr * 64;
    float bcol[4];
#pragma unroll
    for (int nf = 0; nf < 4; ++nf) bcol[nf] = bias[col0 + nf * 16 + lr];
#pragma unroll
    for (int mf = 0; mf < 4; ++mf) {
#pragma unroll
        for (int r = 0; r < 4; ++r) {
            const int row = row0 + mf * 16 + (lane >> 4) * 4 + r;
            float nrm = 0.f;
#pragma unroll
            for (int nf = 0; nf < 4; ++nf) {
                float v = acc[mf][nf][r] + bcol[nf];
                C[(size_t)row * 1024 + col0 + nf * 16 + lr] = f2bf(v);
                nrm += v * v;
            }
#pragma unroll
            for (int off = 1; off < 16; off <<= 1) nrm += __shfl_xor(nrm, off, 64);
            if (lr == 0) atomicAdd(&wgn2[row], nrm);
        }
    }
}

// ---------- per-batch graph algebra (unchanged) ----------
__global__ __launch_bounds__(64) void k_batch(const u16* __restrict__ xb,
                                              const u16* __restrict__ wgb,
                                              const float* __restrict__ xinv,
                                              const float* __restrict__ wgn2,
                                              const float* __restrict__ matrix,
                                              const float* __restrict__ a_param,
                                              float* __restrict__ ascores,
                                              float* __restrict__ e2_out,
                                              float* __restrict__ m_out) {
    const int b = blockIdx.x, l = threadIdx.x;
    const int j = l & 15, ig = (l >> 4) * 4;
    const size_t roff = (size_t)(b * 16 + j) * 1024 + (l >> 4) * 8;
    f32x4 acc0 = {}, acc1 = {};
#pragma unroll
    for (int kt = 0; kt < 1024; kt += 64) {
        short8 xa0 = *(const short8*)(xb + roff + kt);
        short8 wa0 = *(const short8*)(wgb + roff + kt);
        short8 xa1 = *(const short8*)(xb + roff + kt + 32);
        short8 wa1 = *(const short8*)(wgb + roff + kt + 32);
        acc0 = __builtin_amdgcn_mfma_f32_16x16x32_bf16(xa0, wa0, acc0, 0, 0, 0);
        acc1 = __builtin_amdgcn_mfma_f32_16x16x32_bf16(xa1, wa1, acc1, 0, 0, 0);
    }
    const float inw = 1.0f / fmaxf(sqrtf(wgn2[b * 16 + j]), 1e-12f);
    const float boost = 1.0f + a_param[0];
    float e[4];
#pragma unroll
    for (int r = 0; r < 4; ++r) {
        const int i = ig + r;
        float v = (acc0[r] + acc1[r]) * xinv[b * 16 + i] * inw;
        if (i == j) v *= boost;
        e[r] = v;
        ascores[(size_t)b * 256 + i * 16 + j] = v;
    }
    float mx = fmaxf(fmaxf(e[0], e[1]), fmaxf(e[2], e[3]));
    mx = fmaxf(mx, __shfl_xor(mx, 16, 64));
    mx = fmaxf(mx, __shfl_xor(mx, 32, 64));
    float p[4], s = 0.f;
#pragma unroll
    for (int r = 0; r < 4; ++r) { p[r] = __expf(e[r] - mx); s += p[r]; }
    s += __shfl_xor(s, 16, 64);
    s += __shfl_xor(s, 32, 64);
    const float invs = 1.0f / s;

    __shared__ float esm_l[16 * 17];
    __shared__ float fi_l[16 * 17];
    __shared__ float e2_l[16 * 17];
    __shared__ float m_l[256];
#pragma unroll
    for (int r = 0; r < 4; ++r) esm_l[(ig + r) * 17 + j] = p[r] * invs;
    const f32x4 mv = *(const f32x4*)(matrix + (size_t)b * 256 + 4 * l);
    *(f32x4*)(m_l + 4 * l) = mv;
    *(f32x4*)(m_out + (size_t)b * 256 + 4 * l) = mv;
    __syncthreads();
    float fi[4] = {0, 0, 0, 0};
#pragma unroll
    for (int t = 0; t < 16; ++t) {
        const float mk = m_l[t * 16 + j];
#pragma unroll
        for (int r = 0; r < 4; ++r) fi[r] += esm_l[(ig + r) * 17 + t] * mk;
    }
#pragma unroll
    for (int r = 0; r < 4; ++r) fi_l[(ig + r) * 17 + j] = fi[r];
    __syncthreads();
    float e2v[4] = {0, 0, 0, 0};
#pragma unroll
    for (int kk = 0; kk < 16; ++kk) {
        const float w = esm_l[j * 17 + kk] * m_l[kk * 16 + kk];
#pragma unroll
        for (int r = 0; r < 4; ++r) e2v[r] += fi_l[(ig + r) * 17 + kk] * w;
    }
#pragma unroll
    for (int r = 0; r < 4; ++r) e2_l[(ig + r) * 17 + j] = e2v[r];
    __syncthreads();
#pragma unroll
    for (int r = 0; r < 4; ++r) {
        const int i = ig + r;
        e2_out[(size_t)b * 256 + i * 16 + j] = 0.5f * (e2_l[i * 17 + j] + e2_l[j * 17 + i]);
    }
}

// ---------- attn[b,i,f] = tanh(sum_j ascores[b,j,i] * x[b,j,f]) -> bf16 ----------
__global__ __launch_bounds__(256) void k_attn(const float* __restrict__ x,
                                              const float* __restrict__ ascores,
                                              u16* __restrict__ attn_bf) {
    __shared__ float xl[16][256];
    __shared__ float as_l[256];
    const int b = blockIdx.y, f0 = blockIdx.x * 256, t = threadIdx.x;
    as_l[t] = ascores[(size_t)b * 256 + t];
#pragma unroll
    for (int jj = 0; jj < 16; ++jj)
        xl[jj][t] = x[((size_t)b * 16 + jj) * 1024 + f0 + t];
    __syncthreads();
    float accv[16] = {};
#pragma unroll
    for (int jj = 0; jj < 16; ++jj) {
        const float xv = xl[jj][t];
#pragma unroll
        for (int i = 0; i < 16; ++i) accv[i] = fmaf(as_l[jj * 16 + i], xv, accv[i]);
    }
#pragma unroll
    for (int i = 0; i < 16; ++i)
        attn_bf[((size_t)b * 16 + i) * 1024 + f0 + t] = f2bf(tanhf(accv[i]));
}

// ================= GEMM2: 256x256 8-phase template, split-K=4, bf16 partials =================
#define MFMA16(a, b, c) __builtin_amdgcn_mfma_f32_16x16x32_bf16(a, b, c, 0, 0, 0)
#define SBAR() __builtin_amdgcn_s_barrier()
#define LGKM0() do { asm volatile("s_waitcnt lgkmcnt(0)" ::: "memory"); __builtin_amdgcn_sched_barrier(0); } while (0)
#define SCHED0() __builtin_amdgcn_sched_barrier(0)
#define VMW4 asm volatile("s_waitcnt vmcnt(4)" ::: "memory")
#define VMW2 asm volatile("s_waitcnt vmcnt(2)" ::: "memory")
#define VMW0 asm volatile("s_waitcnt vmcnt(0)" ::: "memory")
#define VMNOP do {} while (0)

// One K-tile (BK=64) = 4 phases. Chunk issue order: Ach0, Bch0, Bch1, Ach1.
// vmcnt placed BEFORE the phase-end barrier => cross-wave completeness at barrier.
#define DO_TILE(ISS, VMA, VMB, VMD)                                           \
  do {                                                                        \
    short8 Af[4][2], Bf0[2][2], Bf1[2][2];                                    \
    /* ---- phase 0: read Ach0(mf0-3)+Bch0(nf0-1), issue next Ach0 ---- */    \
    _Pragma("unroll") for (int m = 0; m < 4; ++m) {                           \
      Af[m][0] = *(const short8*)(la + rpA[m] + sw0);                         \
      Af[m][1] = *(const short8*)(la + rpA[m] + sw1);                         \
    }                                                                         \
    _Pragma("unroll") for (int n = 0; n < 2; ++n) {                           \
      Bf0[n][0] = *(const short8*)(lb + rpB[n] + sw0);                        \
      Bf0[n][1] = *(const short8*)(lb + rpB[n] + sw1);                        \
    }                                                                         \
    if (ISS) { gll16(AG + (saO00 + knx), danext + ldst);                      \
               gll16(AG + (saO01 + knx), danext + 4096 + ldst); }             \
    SBAR(); LGKM0();                                                          \
    __builtin_amdgcn_s_setprio(1);                                            \
    _Pragma("unroll") for (int m = 0; m < 4; ++m)                             \
      _Pragma("unroll") for (int n = 0; n < 2; ++n) {                         \
        acc[m][n] = MFMA16(Af[m][0], Bf0[n][0], acc[m][n]);                   \
        acc[m][n] = MFMA16(Af[m][1], Bf0[n][1], acc[m][n]);                   \
      }                                                                       \
    __builtin_amdgcn_s_setprio(0); SCHED0(); VMA; SBAR();                     \
    /* ---- phase 1: read Bch1(nf2-3), issue next Bch0 ---- */                \
    _Pragma("unroll") for (int n = 0; n < 2; ++n) {                           \
      Bf1[n][0] = *(const short8*)(lb + rpB[n + 2] + sw0);                    \
      Bf1[n][1] = *(const short8*)(lb + rpB[n + 2] + sw1);                    \
    }                                                                         \
    if (ISS) { gll16(BG + (sbO00 + knx), dbnext + ldst);                      \
               gll16(BG + (sbO01 + knx), dbnext + 4096 + ldst); }             \
    SBAR(); LGKM0();                                                          \
    __builtin_amdgcn_s_setprio(1);                                            \
    _Pragma("unroll") for (int m = 0; m < 4; ++m)                             \
      _Pragma("unroll") for (int n = 0; n < 2; ++n) {                         \
        acc[m][n + 2] = MFMA16(Af[m][0], Bf1[n][0], acc[m][n + 2]);           \
        acc[m][n + 2] = MFMA16(Af[m][1], Bf1[n][1], acc[m][n + 2]);           \
      }                                                                       \
    __builtin_amdgcn_s_setprio(0); SCHED0(); VMB; SBAR();                     \
    /* ---- phase 2: read Ach1(mf4-7), issue next Bch1 ---- */                \
    _Pragma("unroll") for (int m = 0; m < 4; ++m) {                           \
      Af[m][0] = *(const short8*)(la + rpA[m + 4] + sw0);                     \
      Af[m][1] = *(const short8*)(la + rpA[m + 4] + sw1);                     \
    }                                                                         \
    if (ISS) { gll16(BG + (sbO10 + knx), dbnext + 8192 + ldst);               \
               gll16(BG + (sbO11 + knx), dbnext + 8192 + 4096 + ldst); }      \
    SBAR(); LGKM0();                                                          \
    __builtin_amdgcn_s_setprio(1);                                            \
    _Pragma("unroll") for (int m = 0; m < 4; ++m)                             \
      _Pragma("unroll") for (int n = 0; n < 2; ++n) {                         \
        acc[m + 4][n] = MFMA16(Af[m][0], Bf0[n][0], acc[m + 4][n]);           \
        acc[m + 4][n] = MFMA16(Af[m][1], Bf0[n][1], acc[m + 4][n]);           \
      }                                                                       \
    __builtin_amdgcn_s_setprio(0); SCHED0(); SBAR();                          \
    /* ---- phase 3: no reads, issue next Ach1 ---- */                        \
    if (ISS) { gll16(AG + (saO10 + knx), danext + 8192 + ldst);               \
               gll16(AG + (saO11 + knx), danext + 8192 + 4096 + ldst); }      \
    __builtin_amdgcn_s_setprio(1);                                            \
    _Pragma("unroll") for (int m = 0; m < 4; ++m)                             \
      _Pragma("unroll") for (int n = 0; n < 2; ++n) {                         \
        acc[m + 4][n + 2] = MFMA16(Af[m][0], Bf1[n][0], acc[m + 4][n + 2]);   \
        acc[m + 4][n + 2] = MFMA16(Af[m][1], Bf1[n][1], acc[m + 4][n + 2]);   \
      }                                                                       \
    __builtin_amdgcn_s_setprio(0); SCHED0(); VMD; SBAR();                     \
  } while (0)

__global__ __launch_bounds__(512, 2) void k_gemm2_8ph(const u16* __restrict__ AG,
                                                      const u16* __restrict__ BG,
                                                      u16* __restrict__ part) {
    __shared__ __align__(16) u16 LsA[2][16384];
    __shared__ __align__(16) u16 LsB[2][16384];
    const int K = 16384, NT = 64;
    // grid 256 = 4 mtiles x 4 z x 16 ntiles; bijective XCD swizzle (nwg%8==0)
    const int lin = blockIdx.x;
    const int w = (lin & 7) * 32 + (lin >> 3);
    const int m0 = (w & 3) * 256;
    const int z = (w >> 2) & 3;
    const int n0 = (w >> 4) * 256;
    const int kbeg = z * 4096;

    const int tid = threadIdx.x, wave = tid >> 6, lane = tid & 63;
    const int lr = lane & 15, kq = lane >> 4;
    const int wr = wave >> 2, wc = wave & 3;

    // staging source offsets (u32 elems), XOR-swizzled at 16B-granule level
    const int trow = tid >> 3;
    const u32 swsrc = (u32)(((tid & 7) ^ (trow & 7)) * 8);
    const u32 saO00 = (u32)(m0 + 0 * 128 + 0 * 64 + trow) * (u32)K + (u32)kbeg + swsrc;
    const u32 saO01 = (u32)(m0 + 1 * 128 + 0 * 64 + trow) * (u32)K + (u32)kbeg + swsrc;
    const u32 saO10 = (u32)(m0 + 0 * 128 + 1 * 64 + trow) * (u32)K + (u32)kbeg + swsrc;
    const u32 saO11 = (u32)(m0 + 1 * 128 + 1 * 64 + trow) * (u32)K + (u32)kbeg + swsrc;
    const int q0 = trow, q1 = 64 + trow;
    const u32 sbO00 = (u32)(n0 + (q0 >> 5) * 64 + 0 * 32 + (q0 & 31)) * (u32)K + (u32)kbeg + swsrc;
    const u32 sbO01 = (u32)(n0 + (q1 >> 5) * 64 + 0 * 32 + (q1 & 31)) * (u32)K + (u32)kbeg + swsrc;
    const u32 sbO10 = (u32)(n0 + (q0 >> 5) * 64 + 1 * 32 + (q0 & 31)) * (u32)K + (u32)kbeg + swsrc;
    const u32 sbO11 = (u32)(n0 + (q1 >> 5) * 64 + 1 * 32 + (q1 & 31)) * (u32)K + (u32)kbeg + swsrc;
    const u32 ldst = (u32)wave * 512;  // wave-uniform LDS dest base (elems)

    // read-side physical row bases (elems; *64 per row) and swizzled k-granule offsets
    int rpA[8], rpB[4];
#pragma unroll
    for (int mf = 0; mf < 8; ++mf)
        rpA[mf] = ((mf >> 2) * 128 + wr * 64 + (mf & 3) * 16 + lr) << 6;
#pragma unroll
    for (int nf = 0; nf < 4; ++nf)
        rpB[nf] = ((nf >> 1) * 128 + wc * 32 + (nf & 1) * 16 + lr) << 6;
    const int sw0 = ((0 + kq) ^ (lr & 7)) * 8;
    const int sw1 = ((4 + kq) ^ (lr & 7)) * 8;

    f32x4 acc[8][4] = {};

    // prologue: stage tile0 in consumption order Ach0, Bch0, Bch1, Ach1
    gll16(AG + saO00, &LsA[0][0] + ldst);
    gll16(AG + saO01, &LsA[0][0] + 4096 + ldst);
    gll16(BG + sbO00, &LsB[0][0] + ldst);
    gll16(BG + sbO01, &LsB[0][0] + 4096 + ldst);
    gll16(BG + sbO10, &LsB[0][0] + 8192 + ldst);
    gll16(BG + sbO11, &LsB[0][0] + 8192 + 4096 + ldst);
    gll16(AG + saO10, &LsA[0][0] + 8192 + ldst);
    gll16(AG + saO11, &LsA[0][0] + 8192 + 4096 + ldst);
    VMW4;
    SBAR();

    int cur = 0;
    u32 ko = 64;
    for (int T = 0; T < NT - 1; ++T) {
        const u16* la = &LsA[cur][0];
        const u16* lb = &LsB[cur][0];
        u16* danext = &LsA[cur ^ 1][0];
        u16* dbnext = &LsB[cur ^ 1][0];
        const u32 knx = ko;
        DO_TILE(1, VMW4, VMW4, VMW4);
        cur ^= 1;
        ko += 64;
    }
    {   // last tile: no prefetch; drains 2 -> 0
        const u16* la = &LsA[cur][0];
        const u16* lb = &LsB[cur][0];
        u16* danext = &LsA[cur ^ 1][0];
        u16* dbnext = &LsB[cur ^ 1][0];
        const u32 knx = 0;
        (void)danext; (void)dbnext;
        DO_TILE(0, VMW2, VMW0, VMNOP);
    }

    // epilogue: bf16 partial store
    u16* po = part + (size_t)z * 4194304ull;
    const int col0 = n0 + wc * 64;
    const int row0 = m0 + wr * 128;
#pragma unroll
    for (int mf = 0; mf < 8; ++mf)
#pragma unroll
        for (int r = 0; r < 4; ++r) {
            const int row = row0 + mf * 16 + kq * 4 + r;
#pragma unroll
            for (int nf = 0; nf < 4; ++nf)
                po[(size_t)row * 4096 + col0 + nf * 16 + lr] = f2bf(acc[mf][nf][r]);
        }
}

// ---------- broadcast: out[b, rep, :] = sum_z p[z][b,:] + b_mlp ----------
__global__ __launch_bounds__(256) void k_bcast(const u16* __restrict__ p,
                                               const float* __restrict__ bias,
                                               float* __restrict__ out) {
    const size_t i = (size_t)blockIdx.x * 256 + threadIdx.x;  // 16,777,216 float4
    const int o4 = (int)(i & 1023);
    const int b = (int)(i >> 14);
    const size_t src = (size_t)b * 4096 + (size_t)o4 * 4;
    f32x4 r = *(const f32x4*)(bias + (size_t)o4 * 4);
#pragma unroll
    for (int z = 0; z < 4; ++z) {
        us4 v = *(const us4*)(p + (size_t)z * 4194304ull + src);
        r.x += bf2f(v.x); r.y += bf2f(v.y); r.z += bf2f(v.z); r.w += bf2f(v.w);
    }
    *(f32x4*)(out + i * 4) = r;
}

extern "C" void kernel_launch(void* const* d_in, const int* in_sizes, int n_in,
                              void* d_out, int out_size, void* d_ws, size_t ws_size,
                              hipStream_t stream) {
    const float* x      = (const float*)d_in[0];
    const float* matrix = (const float*)d_in[1];
    const float* W1     = (const float*)d_in[2];
    const float* b1     = (const float*)d_in[3];
    const float* W_mlp  = (const float*)d_in[4];
    const float* b_mlp  = (const float*)d_in[5];
    const float* a_par  = (const float*)d_in[6];
    float* out = (float*)d_out;

    char* ws = (char*)d_ws;
    size_t off = 0;
    auto alloc = [&](size_t bytes) {
        char* p = ws + off;
        off += (bytes + 255) & ~(size_t)255;
        return p;
    };
    u16*   x_bf  = (u16*)alloc(16384ull * 1024 * 2);    // reused as attn_bf after k_batch
    u16*   wg_bf = (u16*)alloc(16384ull * 1024 * 2);    // reused as GEMM2 bf16 partials (4 x 8MB)
    u16*   w1_bf = (u16*)alloc(1024ull * 1024 * 2);
    u16*   wm_bf = (u16*)alloc(4096ull * 16384 * 2);
    float* xinv  = (float*)alloc(16384ull * 4);
    float* wgn2  = (float*)alloc(16384ull * 4);
    float* ascr  = (float*)alloc(1024ull * 256 * 4);
    u16*   attn_bf = x_bf;
    u16*   part    = wg_bf;
    float* e2_out = out + 67108864ull;
    float* m_out  = out + 67371008ull;

    hipMemsetAsync(wgn2, 0, 16384 * 4, stream);
    k_cvt_x<<<16384, 256, 0, stream>>>(x, x_bf, xinv);
    k_cvt<<<1024, 256, 0, stream>>>(W1, w1_bf);
    k_cvt<<<65536, 256, 0, stream>>>(W_mlp, wm_bf);
    k_gemm1<<<1024, 256, 0, stream>>>(x_bf, w1_bf, b1, wg_bf, wgn2);
    k_batch<<<1024, 64, 0, stream>>>(x_bf, wg_bf, xinv, wgn2, matrix, a_par,
                                     ascr, e2_out, m_out);
    k_attn<<<dim3(4, 1024), 256, 0, stream>>>(x, ascr, attn_bf);
    k_gemm2_8ph<<<256, 512, 0, stream>>>(attn_bf, wm_bf, part);
    k_bcast<<<65536, 256, 0, stream>>>(part, b_mlp, out);
}

// Round 4
// 409.258 us; speedup vs baseline: 1.4893x; 1.2201x over previous
//
#include <hip/hip_runtime.h>
#include <math.h>

typedef short short8 __attribute__((ext_vector_type(8)));
typedef float f32x4 __attribute__((ext_vector_type(4)));
typedef unsigned short us4 __attribute__((ext_vector_type(4)));
typedef unsigned int u32x4 __attribute__((ext_vector_type(4)));
typedef unsigned short u16;
typedef unsigned int u32;

#define GAS __attribute__((address_space(1)))
#define LAS __attribute__((address_space(3)))

static __device__ __forceinline__ u16 f2bf(float f) {
    union { float f; u32 u; } v; v.f = f;
    u32 r = v.u + 0x7FFFu + ((v.u >> 16) & 1u);
    return (u16)(r >> 16);
}

static __device__ __forceinline__ u32 pk2(float a, float b) {
    return (u32)f2bf(a) | ((u32)f2bf(b) << 16);
}

static __device__ __forceinline__ float bf2f(u16 h) {
    union { u32 u; float f; } v; v.u = ((u32)h) << 16;
    return v.f;
}

static __device__ __forceinline__ void gll16(const void* g, void* l) {
    __builtin_amdgcn_global_load_lds((const GAS void*)g, (LAS void*)l, 16, 0, 0);
}

// ---------- convert x rows to bf16 + row inverse norms ----------
__global__ __launch_bounds__(256) void k_cvt_x(const float* __restrict__ x,
                                               u16* __restrict__ xb,
                                               float* __restrict__ xinv) {
    const int row = blockIdx.x, t = threadIdx.x;
    const f32x4 v = *(const f32x4*)(x + (size_t)row * 1024 + 4 * t);
    u32* dst = (u32*)(xb + (size_t)row * 1024 + 4 * t);
    dst[0] = pk2(v.x, v.y); dst[1] = pk2(v.z, v.w);
    float s = v.x * v.x + v.y * v.y + v.z * v.z + v.w * v.w;
#pragma unroll
    for (int off = 1; off < 64; off <<= 1) s += __shfl_xor(s, off, 64);
    __shared__ float red[4];
    if ((t & 63) == 0) red[t >> 6] = s;
    __syncthreads();
    if (t == 0)
        xinv[row] = 1.0f / fmaxf(sqrtf(red[0] + red[1] + red[2] + red[3]), 1e-12f);
}

// ---------- generic f32 -> bf16 convert (W1 only now) ----------
__global__ __launch_bounds__(256) void k_cvt(const float* __restrict__ in,
                                             u16* __restrict__ out) {
    const size_t i = (size_t)blockIdx.x * 256 + threadIdx.x;
    const f32x4 v = *(const f32x4*)(in + 4 * i);
    u32* dst = (u32*)(out + 4 * i);
    dst[0] = pk2(v.x, v.y); dst[1] = pk2(v.z, v.w);
}

// ================= shared 8-phase machinery =================
#define MFMA16(a, b, c) __builtin_amdgcn_mfma_f32_16x16x32_bf16(a, b, c, 0, 0, 0)
#define SBAR() __builtin_amdgcn_s_barrier()
#define LGKM0() do { asm volatile("s_waitcnt lgkmcnt(0)" ::: "memory"); __builtin_amdgcn_sched_barrier(0); } while (0)
#define SCHED0() __builtin_amdgcn_sched_barrier(0)
#define VMW12 asm volatile("s_waitcnt vmcnt(12)" ::: "memory")
#define VMW4 asm volatile("s_waitcnt vmcnt(4)" ::: "memory")
#define VMW2 asm volatile("s_waitcnt vmcnt(2)" ::: "memory")
#define VMW0 asm volatile("s_waitcnt vmcnt(0)" ::: "memory")
#define VMW2L asm volatile("s_waitcnt vmcnt(2) lgkmcnt(0)" ::: "memory")
#define VMNOP do {} while (0)

// -------- pure-gll16 tile (A,B both bf16 in global): used by GEMM1 --------
#define DO_TILE(ISS, VMA, VMB, VMD)                                           \
  do {                                                                        \
    short8 Af[4][2], Bf0[2][2], Bf1[2][2];                                    \
    _Pragma("unroll") for (int m = 0; m < 4; ++m) {                           \
      Af[m][0] = *(const short8*)(la + rpA[m] + sw0);                         \
      Af[m][1] = *(const short8*)(la + rpA[m] + sw1);                         \
    }                                                                         \
    _Pragma("unroll") for (int n = 0; n < 2; ++n) {                           \
      Bf0[n][0] = *(const short8*)(lb + rpB[n] + sw0);                        \
      Bf0[n][1] = *(const short8*)(lb + rpB[n] + sw1);                        \
    }                                                                         \
    if (ISS) { gll16(AG + (saO00 + knx), danext + ldst);                      \
               gll16(AG + (saO01 + knx), danext + 4096 + ldst); }             \
    SBAR(); LGKM0();                                                          \
    __builtin_amdgcn_s_setprio(1);                                            \
    _Pragma("unroll") for (int m = 0; m < 4; ++m)                             \
      _Pragma("unroll") for (int n = 0; n < 2; ++n) {                         \
        acc[m][n] = MFMA16(Af[m][0], Bf0[n][0], acc[m][n]);                   \
        acc[m][n] = MFMA16(Af[m][1], Bf0[n][1], acc[m][n]);                   \
      }                                                                       \
    __builtin_amdgcn_s_setprio(0); SCHED0(); VMA; SBAR();                     \
    _Pragma("unroll") for (int n = 0; n < 2; ++n) {                           \
      Bf1[n][0] = *(const short8*)(lb + rpB[n + 2] + sw0);                    \
      Bf1[n][1] = *(const short8*)(lb + rpB[n + 2] + sw1);                    \
    }                                                                         \
    if (ISS) { gll16(BG + (sbO00 + knx), dbnext + ldst);                      \
               gll16(BG + (sbO01 + knx), dbnext + 4096 + ldst); }             \
    SBAR(); LGKM0();                                                          \
    __builtin_amdgcn_s_setprio(1);                                            \
    _Pragma("unroll") for (int m = 0; m < 4; ++m)                             \
      _Pragma("unroll") for (int n = 0; n < 2; ++n) {                         \
        acc[m][n + 2] = MFMA16(Af[m][0], Bf1[n][0], acc[m][n + 2]);           \
        acc[m][n + 2] = MFMA16(Af[m][1], Bf1[n][1], acc[m][n + 2]);           \
      }                                                                       \
    __builtin_amdgcn_s_setprio(0); SCHED0(); VMB; SBAR();                     \
    _Pragma("unroll") for (int m = 0; m < 4; ++m) {                           \
      Af[m][0] = *(const short8*)(la + rpA[m + 4] + sw0);                     \
      Af[m][1] = *(const short8*)(la + rpA[m + 4] + sw1);                     \
    }                                                                         \
    if (ISS) { gll16(BG + (sbO10 + knx), dbnext + 8192 + ldst);               \
               gll16(BG + (sbO11 + knx), dbnext + 8192 + 4096 + ldst); }      \
    SBAR(); LGKM0();                                                          \
    __builtin_amdgcn_s_setprio(1);                                            \
    _Pragma("unroll") for (int m = 0; m < 4; ++m)                             \
      _Pragma("unroll") for (int n = 0; n < 2; ++n) {                         \
        acc[m + 4][n] = MFMA16(Af[m][0], Bf0[n][0], acc[m + 4][n]);           \
        acc[m + 4][n] = MFMA16(Af[m][1], Bf0[n][1], acc[m + 4][n]);           \
      }                                                                       \
    __builtin_amdgcn_s_setprio(0); SCHED0(); SBAR();                          \
    if (ISS) { gll16(AG + (saO10 + knx), danext + 8192 + ldst);               \
               gll16(AG + (saO11 + knx), danext + 8192 + 4096 + ldst); }      \
    __builtin_amdgcn_s_setprio(1);                                            \
    _Pragma("unroll") for (int m = 0; m < 4; ++m)                             \
      _Pragma("unroll") for (int n = 0; n < 2; ++n) {                         \
        acc[m + 4][n + 2] = MFMA16(Af[m][0], Bf1[n][0], acc[m + 4][n + 2]);   \
        acc[m + 4][n + 2] = MFMA16(Af[m][1], Bf1[n][1], acc[m + 4][n + 2]);   \
      }                                                                       \
    __builtin_amdgcn_s_setprio(0); SCHED0(); VMD; SBAR();                     \
  } while (0)

// -------- mixed tile: A bf16 via gll16, B f32 reg-staged with fused cvt (GEMM2) --------
// ph0: rd Ach0+Bch0, issue 8 B f32 loads(t+1)       | MFMA q0
// ph1: rd Bch1,      issue 4 A gll16(t+1)           | MFMA q1 | WA
// ph2: rd Ach1                                      | MFMA q2 | cvt+write Bch0/1(t+1)
// ph3:                                              | MFMA q3 | cvt+write Bch2/3(t+1) | WEND
#define DO_TILE2(ISS, WA, WEND)                                               \
  do {                                                                        \
    short8 Af[4][2], Bf0[2][2], Bf1[2][2];                                    \
    f32x4 bn[8];                                                              \
    _Pragma("unroll") for (int m = 0; m < 4; ++m) {                           \
      Af[m][0] = *(const short8*)(la + rpA[m] + sw0);                         \
      Af[m][1] = *(const short8*)(la + rpA[m] + sw1);                         \
    }                                                                         \
    _Pragma("unroll") for (int n = 0; n < 2; ++n) {                           \
      Bf0[n][0] = *(const short8*)(lb + rpB[n] + sw0);                        \
      Bf0[n][1] = *(const short8*)(lb + rpB[n] + sw1);                        \
    }                                                                         \
    if (ISS) {                                                                \
      _Pragma("unroll") for (int c = 0; c < 4; ++c) {                         \
        bn[2 * c]     = *(const f32x4*)(BGf + bro[c] + knx + swsrc);          \
        bn[2 * c + 1] = *(const f32x4*)(BGf + bro[c] + knx + swsrc + 4);      \
      }                                                                       \
    }                                                                         \
    SBAR(); LGKM0();                                                          \
    __builtin_amdgcn_s_setprio(1);                                            \
    _Pragma("unroll") for (int m = 0; m < 4; ++m)                             \
      _Pragma("unroll") for (int n = 0; n < 2; ++n) {                         \
        acc[m][n] = MFMA16(Af[m][0], Bf0[n][0], acc[m][n]);                   \
        acc[m][n] = MFMA16(Af[m][1], Bf0[n][1], acc[m][n]);                   \
      }                                                                       \
    __builtin_amdgcn_s_setprio(0); SCHED0(); SBAR();                          \
    _Pragma("unroll") for (int n = 0; n < 2; ++n) {                           \
      Bf1[n][0] = *(const short8*)(lb + rpB[n + 2] + sw0);                    \
      Bf1[n][1] = *(const short8*)(lb + rpB[n + 2] + sw1);                    \
    }                                                                         \
    if (ISS) {                                                                \
      gll16(AG + (saO00 + knx), danext + ldst);                               \
      gll16(AG + (saO01 + knx), danext + 4096 + ldst);                        \
      gll16(AG + (saO10 + knx), danext + 8192 + ldst);                        \
      gll16(AG + (saO11 + knx), danext + 8192 + 4096 + ldst);                 \
    }                                                                         \
    SBAR(); LGKM0();                                                          \
    __builtin_amdgcn_s_setprio(1);                                            \
    _Pragma("unroll") for (int m = 0; m < 4; ++m)                             \
      _Pragma("unroll") for (int n = 0; n < 2; ++n) {                         \
        acc[m][n + 2] = MFMA16(Af[m][0], Bf1[n][0], acc[m][n + 2]);           \
        acc[m][n + 2] = MFMA16(Af[m][1], Bf1[n][1], acc[m][n + 2]);           \
      }                                                                       \
    __builtin_amdgcn_s_setprio(0); SCHED0(); WA; SBAR();                      \
    _Pragma("unroll") for (int m = 0; m < 4; ++m) {                           \
      Af[m][0] = *(const short8*)(la + rpA[m + 4] + sw0);                     \
      Af[m][1] = *(const short8*)(la + rpA[m + 4] + sw1);                     \
    }                                                                         \
    SBAR(); LGKM0();                                                          \
    __builtin_amdgcn_s_setprio(1);                                            \
    _Pragma("unroll") for (int m = 0; m < 4; ++m)                             \
      _Pragma("unroll") for (int n = 0; n < 2; ++n) {                         \
        acc[m + 4][n] = MFMA16(Af[m][0], Bf0[n][0], acc[m + 4][n]);           \
        acc[m + 4][n] = MFMA16(Af[m][1], Bf0[n][1], acc[m + 4][n]);           \
      }                                                                       \
    __builtin_amdgcn_s_setprio(0); SCHED0();                                  \
    if (ISS) {                                                                \
      _Pragma("unroll") for (int c = 0; c < 2; ++c) {                         \
        u32x4 wv;                                                             \
        wv.x = pk2(bn[2 * c].x, bn[2 * c].y);                                 \
        wv.y = pk2(bn[2 * c].z, bn[2 * c].w);                                 \
        wv.z = pk2(bn[2 * c + 1].x, bn[2 * c + 1].y);                         \
        wv.w = pk2(bn[2 * c + 1].z, bn[2 * c + 1].w);                         \
        *(u32x4*)(dbnext + c * 4096 + (tid << 3)) = wv;                       \
      }                                                                       \
    }                                                                         \
    SBAR();                                                                   \
    __builtin_amdgcn_s_setprio(1);                                            \
    _Pragma("unroll") for (int m = 0; m < 4; ++m)                             \
      _Pragma("unroll") for (int n = 0; n < 2; ++n) {                         \
        acc[m + 4][n + 2] = MFMA16(Af[m][0], Bf1[n][0], acc[m + 4][n + 2]);   \
        acc[m + 4][n + 2] = MFMA16(Af[m][1], Bf1[n][1], acc[m + 4][n + 2]);   \
      }                                                                       \
    __builtin_amdgcn_s_setprio(0); SCHED0();                                  \
    if (ISS) {                                                                \
      _Pragma("unroll") for (int c = 2; c < 4; ++c) {                         \
        u32x4 wv;                                                             \
        wv.x = pk2(bn[2 * c].x, bn[2 * c].y);                                 \
        wv.y = pk2(bn[2 * c].z, bn[2 * c].w);                                 \
        wv.z = pk2(bn[2 * c + 1].x, bn[2 * c + 1].y);                         \
        wv.w = pk2(bn[2 * c + 1].z, bn[2 * c + 1].w);                         \
        *(u32x4*)(dbnext + c * 4096 + (tid << 3)) = wv;                       \
      }                                                                       \
    }                                                                         \
    WEND; SBAR();                                                             \
  } while (0)

// ================= GEMM1: wg = x_bf @ W1_bf^T + b1 (8-phase 256^2) =================
__global__ __launch_bounds__(512, 2) void k_gemm1_8ph(const u16* __restrict__ AG,
                                                      const u16* __restrict__ BG,
                                                      const float* __restrict__ bias,
                                                      u16* __restrict__ C,
                                                      float* __restrict__ wgn2) {
    __shared__ __align__(16) u16 LsA[2][16384];
    __shared__ __align__(16) u16 LsB[2][16384];
    const int K = 1024, NT = 16;
    // grid 256 = 64 m x 4 n; bijective XCD swizzle, n fastest (A-panel reuse; W1 L2-fits)
    const int lin = blockIdx.x;
    const int w = (lin & 7) * 32 + (lin >> 3);
    const int n0 = (w & 3) * 256;
    const int m0 = (w >> 2) * 256;

    const int tid = threadIdx.x, wave = tid >> 6, lane = tid & 63;
    const int lr = lane & 15, kq = lane >> 4;
    const int wr = wave >> 2, wc = wave & 3;

    const int trow = tid >> 3;
    const u32 swsrc = (u32)(((tid & 7) ^ (trow & 7)) * 8);
    const u32 saO00 = (u32)(m0 + 0 + trow) * (u32)K + swsrc;
    const u32 saO01 = (u32)(m0 + 128 + trow) * (u32)K + swsrc;
    const u32 saO10 = (u32)(m0 + 64 + trow) * (u32)K + swsrc;
    const u32 saO11 = (u32)(m0 + 192 + trow) * (u32)K + swsrc;
    const int q0 = trow, q1 = 64 + trow;
    const u32 sbO00 = (u32)(n0 + (q0 >> 5) * 64 + (q0 & 31)) * (u32)K + swsrc;
    const u32 sbO01 = (u32)(n0 + (q1 >> 5) * 64 + (q1 & 31)) * (u32)K + swsrc;
    const u32 sbO10 = (u32)(n0 + (q0 >> 5) * 64 + 32 + (q0 & 31)) * (u32)K + swsrc;
    const u32 sbO11 = (u32)(n0 + (q1 >> 5) * 64 + 32 + (q1 & 31)) * (u32)K + swsrc;
    const u32 ldst = (u32)wave * 512;

    int rpA[8], rpB[4];
#pragma unroll
    for (int mf = 0; mf < 8; ++mf)
        rpA[mf] = ((mf >> 2) * 128 + wr * 64 + (mf & 3) * 16 + lr) << 6;
#pragma unroll
    for (int nf = 0; nf < 4; ++nf)
        rpB[nf] = ((nf >> 1) * 128 + wc * 32 + (nf & 1) * 16 + lr) << 6;
    const int sw0 = ((0 + kq) ^ (lr & 7)) * 8;
    const int sw1 = ((4 + kq) ^ (lr & 7)) * 8;

    f32x4 acc[8][4] = {};

    gll16(AG + saO00, &LsA[0][0] + ldst);
    gll16(AG + saO01, &LsA[0][0] + 4096 + ldst);
    gll16(BG + sbO00, &LsB[0][0] + ldst);
    gll16(BG + sbO01, &LsB[0][0] + 4096 + ldst);
    gll16(BG + sbO10, &LsB[0][0] + 8192 + ldst);
    gll16(BG + sbO11, &LsB[0][0] + 8192 + 4096 + ldst);
    gll16(AG + saO10, &LsA[0][0] + 8192 + ldst);
    gll16(AG + saO11, &LsA[0][0] + 8192 + 4096 + ldst);
    VMW4;
    SBAR();

    int cur = 0;
    u32 ko = 64;
    for (int T = 0; T < NT - 1; ++T) {
        const u16* la = &LsA[cur][0];
        const u16* lb = &LsB[cur][0];
        u16* danext = &LsA[cur ^ 1][0];
        u16* dbnext = &LsB[cur ^ 1][0];
        const u32 knx = ko;
        DO_TILE(1, VMW4, VMW4, VMW4);
        cur ^= 1;
        ko += 64;
    }
    {
        const u16* la = &LsA[cur][0];
        const u16* lb = &LsB[cur][0];
        u16* danext = &LsA[cur ^ 1][0];
        u16* dbnext = &LsB[cur ^ 1][0];
        const u32 knx = 0;
        (void)danext; (void)dbnext;
        DO_TILE(0, VMW2, VMW0, VMNOP);
    }

    const int col0 = n0 + wc * 64;
    const int row0 = m0 + wr * 128;
    float bcol[4];
#pragma unroll
    for (int nf = 0; nf < 4; ++nf) bcol[nf] = bias[col0 + nf * 16 + lr];
#pragma unroll
    for (int mf = 0; mf < 8; ++mf) {
#pragma unroll
        for (int r = 0; r < 4; ++r) {
            const int row = row0 + mf * 16 + kq * 4 + r;
            float nrm = 0.f;
#pragma unroll
            for (int nf = 0; nf < 4; ++nf) {
                float v = acc[mf][nf][r] + bcol[nf];
                C[(size_t)row * 1024 + col0 + nf * 16 + lr] = f2bf(v);
                nrm += v * v;
            }
#pragma unroll
            for (int off = 1; off < 16; off <<= 1) nrm += __shfl_xor(nrm, off, 64);
            if (lr == 0) atomicAdd(&wgn2[row], nrm);
        }
    }
}

// ================= GEMM2: part[z] = attn_bf @ W_mlp^T (f32 B fused-cvt, 8-phase, split-K=4) ==========
__global__ __launch_bounds__(512, 2) void k_gemm2_8ph(const u16* __restrict__ AG,
                                                      const float* __restrict__ BGf,
                                                      u16* __restrict__ part) {
    __shared__ __align__(16) u16 LsA[2][16384];
    __shared__ __align__(16) u16 LsB[2][16384];
    const int K = 16384, NT = 64;
    const int lin = blockIdx.x;
    const int w = (lin & 7) * 32 + (lin >> 3);
    const int m0 = (w & 3) * 256;
    const int z = (w >> 2) & 3;
    const int n0 = (w >> 4) * 256;
    const int kbeg = z * 4096;

    const int tid = threadIdx.x, wave = tid >> 6, lane = tid & 63;
    const int lr = lane & 15, kq = lane >> 4;
    const int wr = wave >> 2, wc = wave & 3;

    const int trow = tid >> 3;
    const u32 swsrc = (u32)(((tid & 7) ^ (trow & 7)) * 8);
    const u32 saO00 = (u32)(m0 + 0 + trow) * (u32)K + (u32)kbeg + swsrc;
    const u32 saO01 = (u32)(m0 + 128 + trow) * (u32)K + (u32)kbeg + swsrc;
    const u32 saO10 = (u32)(m0 + 64 + trow) * (u32)K + (u32)kbeg + swsrc;
    const u32 saO11 = (u32)(m0 + 192 + trow) * (u32)K + (u32)kbeg + swsrc;
    const int q0 = trow, q1 = 64 + trow;
    // B (f32 W_mlp) per-chunk source row bases, elems
    size_t bro[4];
    bro[0] = (size_t)(n0 + (q0 >> 5) * 64 + (q0 & 31)) * 16384 + kbeg;
    bro[1] = (size_t)(n0 + (q1 >> 5) * 64 + (q1 & 31)) * 16384 + kbeg;
    bro[2] = bro[0] + 32ull * 16384;
    bro[3] = bro[1] + 32ull * 16384;
    const u32 ldst = (u32)wave * 512;

    int rpA[8], rpB[4];
#pragma unroll
    for (int mf = 0; mf < 8; ++mf)
        rpA[mf] = ((mf >> 2) * 128 + wr * 64 + (mf & 3) * 16 + lr) << 6;
#pragma unroll
    for (int nf = 0; nf < 4; ++nf)
        rpB[nf] = ((nf >> 1) * 128 + wc * 32 + (nf & 1) * 16 + lr) << 6;
    const int sw0 = ((0 + kq) ^ (lr & 7)) * 8;
    const int sw1 = ((4 + kq) ^ (lr & 7)) * 8;

    f32x4 acc[8][4] = {};

    // prologue: stage tile 0 (B via reg-cvt, A via gll16), full drain
    {
        f32x4 bn[8];
#pragma unroll
        for (int c = 0; c < 4; ++c) {
            bn[2 * c]     = *(const f32x4*)(BGf + bro[c] + swsrc);
            bn[2 * c + 1] = *(const f32x4*)(BGf + bro[c] + swsrc + 4);
        }
        gll16(AG + saO00, &LsA[0][0] + ldst);
        gll16(AG + saO01, &LsA[0][0] + 4096 + ldst);
        gll16(AG + saO10, &LsA[0][0] + 8192 + ldst);
        gll16(AG + saO11, &LsA[0][0] + 8192 + 4096 + ldst);
#pragma unroll
        for (int c = 0; c < 4; ++c) {
            u32x4 wv;
            wv.x = pk2(bn[2 * c].x, bn[2 * c].y);
            wv.y = pk2(bn[2 * c].z, bn[2 * c].w);
            wv.z = pk2(bn[2 * c + 1].x, bn[2 * c + 1].y);
            wv.w = pk2(bn[2 * c + 1].z, bn[2 * c + 1].w);
            *(u32x4*)(&LsB[0][0] + c * 4096 + (tid << 3)) = wv;
        }
        asm volatile("s_waitcnt vmcnt(0) lgkmcnt(0)" ::: "memory");
        SBAR();
    }

    int cur = 0;
    u32 ko = 64;
    for (int T = 0; T < NT - 1; ++T) {
        const u16* la = &LsA[cur][0];
        const u16* lb = &LsB[cur][0];
        u16* danext = &LsA[cur ^ 1][0];
        u16* dbnext = &LsB[cur ^ 1][0];
        const u32 knx = ko;
        DO_TILE2(1, VMW12, VMW2L);
        cur ^= 1;
        ko += 64;
    }
    {
        const u16* la = &LsA[cur][0];
        const u16* lb = &LsB[cur][0];
        u16* danext = &LsA[cur ^ 1][0];
        u16* dbnext = &LsB[cur ^ 1][0];
        const u32 knx = 0;
        (void)danext; (void)dbnext;
        DO_TILE2(0, VMW0, VMNOP);
    }

    u16* po = part + (size_t)z * 4194304ull;
    const int col0 = n0 + wc * 64;
    const int row0 = m0 + wr * 128;
#pragma unroll
    for (int mf = 0; mf < 8; ++mf)
#pragma unroll
        for (int r = 0; r < 4; ++r) {
            const int row = row0 + mf * 16 + kq * 4 + r;
#pragma unroll
            for (int nf = 0; nf < 4; ++nf)
                po[(size_t)row * 4096 + col0 + nf * 16 + lr] = f2bf(acc[mf][nf][r]);
        }
}

// ---------- per-batch graph algebra ----------
__global__ __launch_bounds__(64) void k_batch(const u16* __restrict__ xb,
                                              const u16* __restrict__ wgb,
                                              const float* __restrict__ xinv,
                                              const float* __restrict__ wgn2,
                                              const float* __restrict__ matrix,
                                              const float* __restrict__ a_param,
                                              float* __restrict__ ascores,
                                              float* __restrict__ e2_out,
                                              float* __restrict__ m_out) {
    const int b = blockIdx.x, l = threadIdx.x;
    const int j = l & 15, ig = (l >> 4) * 4;
    const size_t roff = (size_t)(b * 16 + j) * 1024 + (l >> 4) * 8;
    f32x4 acc0 = {}, acc1 = {};
#pragma unroll
    for (int kt = 0; kt < 1024; kt += 64) {
        short8 xa0 = *(const short8*)(xb + roff + kt);
        short8 wa0 = *(const short8*)(wgb + roff + kt);
        short8 xa1 = *(const short8*)(xb + roff + kt + 32);
        short8 wa1 = *(const short8*)(wgb + roff + kt + 32);
        acc0 = __builtin_amdgcn_mfma_f32_16x16x32_bf16(xa0, wa0, acc0, 0, 0, 0);
        acc1 = __builtin_amdgcn_mfma_f32_16x16x32_bf16(xa1, wa1, acc1, 0, 0, 0);
    }
    const float inw = 1.0f / fmaxf(sqrtf(wgn2[b * 16 + j]), 1e-12f);
    const float boost = 1.0f + a_param[0];
    float e[4];
#pragma unroll
    for (int r = 0; r < 4; ++r) {
        const int i = ig + r;
        float v = (acc0[r] + acc1[r]) * xinv[b * 16 + i] * inw;
        if (i == j) v *= boost;
        e[r] = v;
        ascores[(size_t)b * 256 + i * 16 + j] = v;
    }
    float mx = fmaxf(fmaxf(e[0], e[1]), fmaxf(e[2], e[3]));
    mx = fmaxf(mx, __shfl_xor(mx, 16, 64));
    mx = fmaxf(mx, __shfl_xor(mx, 32, 64));
    float p[4], s = 0.f;
#pragma unroll
    for (int r = 0; r < 4; ++r) { p[r] = __expf(e[r] - mx); s += p[r]; }
    s += __shfl_xor(s, 16, 64);
    s += __shfl_xor(s, 32, 64);
    const float invs = 1.0f / s;

    __shared__ float esm_l[16 * 17];
    __shared__ float fi_l[16 * 17];
    __shared__ float e2_l[16 * 17];
    __shared__ float m_l[256];
#pragma unroll
    for (int r = 0; r < 4; ++r) esm_l[(ig + r) * 17 + j] = p[r] * invs;
    const f32x4 mv = *(const f32x4*)(matrix + (size_t)b * 256 + 4 * l);
    *(f32x4*)(m_l + 4 * l) = mv;
    *(f32x4*)(m_out + (size_t)b * 256 + 4 * l) = mv;
    __syncthreads();
    float fi[4] = {0, 0, 0, 0};
#pragma unroll
    for (int t = 0; t < 16; ++t) {
        const float mk = m_l[t * 16 + j];
#pragma unroll
        for (int r = 0; r < 4; ++r) fi[r] += esm_l[(ig + r) * 17 + t] * mk;
    }
#pragma unroll
    for (int r = 0; r < 4; ++r) fi_l[(ig + r) * 17 + j] = fi[r];
    __syncthreads();
    float e2v[4] = {0, 0, 0, 0};
#pragma unroll
    for (int kk = 0; kk < 16; ++kk) {
        const float wgt = esm_l[j * 17 + kk] * m_l[kk * 16 + kk];
#pragma unroll
        for (int r = 0; r < 4; ++r) e2v[r] += fi_l[(ig + r) * 17 + kk] * wgt;
    }
#pragma unroll
    for (int r = 0; r < 4; ++r) e2_l[(ig + r) * 17 + j] = e2v[r];
    __syncthreads();
#pragma unroll
    for (int r = 0; r < 4; ++r) {
        const int i = ig + r;
        e2_out[(size_t)b * 256 + i * 16 + j] = 0.5f * (e2_l[i * 17 + j] + e2_l[j * 17 + i]);
    }
}

// ---------- attn[b,i,f] = tanh(sum_j ascores[b,j,i] * x[b,j,f]) -> bf16 ----------
__global__ __launch_bounds__(256) void k_attn(const float* __restrict__ x,
                                              const float* __restrict__ ascores,
                                              u16* __restrict__ attn_bf) {
    __shared__ float xl[16][256];
    __shared__ float as_l[256];
    const int b = blockIdx.y, f0 = blockIdx.x * 256, t = threadIdx.x;
    as_l[t] = ascores[(size_t)b * 256 + t];
#pragma unroll
    for (int jj = 0; jj < 16; ++jj)
        xl[jj][t] = x[((size_t)b * 16 + jj) * 1024 + f0 + t];
    __syncthreads();
    float accv[16] = {};
#pragma unroll
    for (int jj = 0; jj < 16; ++jj) {
        const float xv = xl[jj][t];
#pragma unroll
        for (int i = 0; i < 16; ++i) accv[i] = fmaf(as_l[jj * 16 + i], xv, accv[i]);
    }
#pragma unroll
    for (int i = 0; i < 16; ++i)
        attn_bf[((size_t)b * 16 + i) * 1024 + f0 + t] = f2bf(tanhf(accv[i]));
}

// ---------- broadcast: out[b, rep, :] = sum_z part[z][b,:] + b_mlp ----------
__global__ __launch_bounds__(256) void k_bcast(const u16* __restrict__ p,
                                               const float* __restrict__ bias,
                                               float* __restrict__ out) {
    const size_t i = (size_t)blockIdx.x * 256 + threadIdx.x;
    const int o4 = (int)(i & 1023);
    const int b = (int)(i >> 14);
    const size_t src = (size_t)b * 4096 + (size_t)o4 * 4;
    f32x4 r = *(const f32x4*)(bias + (size_t)o4 * 4);
#pragma unroll
    for (int z = 0; z < 4; ++z) {
        us4 v = *(const us4*)(p + (size_t)z * 4194304ull + src);
        r.x += bf2f(v.x); r.y += bf2f(v.y); r.z += bf2f(v.z); r.w += bf2f(v.w);
    }
    *(f32x4*)(out + i * 4) = r;
}

extern "C" void kernel_launch(void* const* d_in, const int* in_sizes, int n_in,
                              void* d_out, int out_size, void* d_ws, size_t ws_size,
                              hipStream_t stream) {
    const float* x      = (const float*)d_in[0];
    const float* matrix = (const float*)d_in[1];
    const float* W1     = (const float*)d_in[2];
    const float* b1     = (const float*)d_in[3];
    const float* W_mlp  = (const float*)d_in[4];
    const float* b_mlp  = (const float*)d_in[5];
    const float* a_par  = (const float*)d_in[6];
    float* out = (float*)d_out;

    char* ws = (char*)d_ws;
    size_t off = 0;
    auto alloc = [&](size_t bytes) {
        char* p = ws + off;
        off += (bytes + 255) & ~(size_t)255;
        return p;
    };
    u16*   x_bf  = (u16*)alloc(16384ull * 1024 * 2);    // reused as attn_bf after k_batch
    u16*   wg_bf = (u16*)alloc(16384ull * 1024 * 2);    // reused as GEMM2 bf16 partials (4 x 8MB)
    u16*   w1_bf = (u16*)alloc(1024ull * 1024 * 2);
    float* xinv  = (float*)alloc(16384ull * 4);
    float* wgn2  = (float*)alloc(16384ull * 4);
    float* ascr  = (float*)alloc(1024ull * 256 * 4);
    u16*   attn_bf = x_bf;
    u16*   part    = wg_bf;
    float* e2_out = out + 67108864ull;
    float* m_out  = out + 67371008ull;

    hipMemsetAsync(wgn2, 0, 16384 * 4, stream);
    k_cvt_x<<<16384, 256, 0, stream>>>(x, x_bf, xinv);
    k_cvt<<<1024, 256, 0, stream>>>(W1, w1_bf);
    k_gemm1_8ph<<<256, 512, 0, stream>>>(x_bf, w1_bf, b1, wg_bf, wgn2);
    k_batch<<<1024, 64, 0, stream>>>(x_bf, wg_bf, xinv, wgn2, matrix, a_par,
                                     ascr, e2_out, m_out);
    k_attn<<<dim3(4, 1024), 256, 0, stream>>>(x, ascr, attn_bf);
    k_gemm2_8ph<<<256, 512, 0, stream>>>(attn_bf, W_mlp, part);
    k_bcast<<<65536, 256, 0, stream>>>(part, b_mlp, out);
}

// Round 5
// 393.463 us; speedup vs baseline: 1.5491x; 1.0401x over previous
//
#include <hip/hip_runtime.h>
#include <math.h>

typedef short short8 __attribute__((ext_vector_type(8)));
typedef float f32x4 __attribute__((ext_vector_type(4)));
typedef unsigned short us4 __attribute__((ext_vector_type(4)));
typedef unsigned int u32x4 __attribute__((ext_vector_type(4)));
typedef unsigned short u16;
typedef unsigned int u32;

#define GAS __attribute__((address_space(1)))
#define LAS __attribute__((address_space(3)))

static __device__ __forceinline__ u16 f2bf(float f) {
    union { float f; u32 u; } v; v.f = f;
    u32 r = v.u + 0x7FFFu + ((v.u >> 16) & 1u);
    return (u16)(r >> 16);
}

static __device__ __forceinline__ u32 pk2(float a, float b) {
    return (u32)f2bf(a) | ((u32)f2bf(b) << 16);
}

// packed f32x2 -> bf16x2 in one instruction (lo = first arg)
static __device__ __forceinline__ u32 cvtpk(float lo, float hi) {
    u32 r;
    asm("v_cvt_pk_bf16_f32 %0, %1, %2" : "=v"(r) : "v"(lo), "v"(hi));
    return r;
}

static __device__ __forceinline__ float bf2f(u16 h) {
    union { u32 u; float f; } v; v.u = ((u32)h) << 16;
    return v.f;
}

static __device__ __forceinline__ void gll16(const void* g, void* l) {
    __builtin_amdgcn_global_load_lds((const GAS void*)g, (LAS void*)l, 16, 0, 0);
}

// ---------- convert x rows to bf16 + row inverse norms ----------
__global__ __launch_bounds__(256) void k_cvt_x(const float* __restrict__ x,
                                               u16* __restrict__ xb,
                                               float* __restrict__ xinv) {
    const int row = blockIdx.x, t = threadIdx.x;
    const f32x4 v = *(const f32x4*)(x + (size_t)row * 1024 + 4 * t);
    u32* dst = (u32*)(xb + (size_t)row * 1024 + 4 * t);
    dst[0] = pk2(v.x, v.y); dst[1] = pk2(v.z, v.w);
    float s = v.x * v.x + v.y * v.y + v.z * v.z + v.w * v.w;
#pragma unroll
    for (int off = 1; off < 64; off <<= 1) s += __shfl_xor(s, off, 64);
    __shared__ float red[4];
    if ((t & 63) == 0) red[t >> 6] = s;
    __syncthreads();
    if (t == 0)
        xinv[row] = 1.0f / fmaxf(sqrtf(red[0] + red[1] + red[2] + red[3]), 1e-12f);
}

// ---------- generic f32 -> bf16 convert (W1 only) ----------
__global__ __launch_bounds__(256) void k_cvt(const float* __restrict__ in,
                                             u16* __restrict__ out) {
    const size_t i = (size_t)blockIdx.x * 256 + threadIdx.x;
    const f32x4 v = *(const f32x4*)(in + 4 * i);
    u32* dst = (u32*)(out + 4 * i);
    dst[0] = pk2(v.x, v.y); dst[1] = pk2(v.z, v.w);
}

// ================= shared 8-phase machinery =================
#define MFMA16(a, b, c) __builtin_amdgcn_mfma_f32_16x16x32_bf16(a, b, c, 0, 0, 0)
#define SBAR() __builtin_amdgcn_s_barrier()
#define LGKM0() do { asm volatile("s_waitcnt lgkmcnt(0)" ::: "memory"); __builtin_amdgcn_sched_barrier(0); } while (0)
#define SCHED0() __builtin_amdgcn_sched_barrier(0)
#define VMW4 asm volatile("s_waitcnt vmcnt(4)" ::: "memory")
#define VMW2 asm volatile("s_waitcnt vmcnt(2)" ::: "memory")
#define VMW0 asm volatile("s_waitcnt vmcnt(0)" ::: "memory")
#define VMW8L asm volatile("s_waitcnt vmcnt(8) lgkmcnt(0)" ::: "memory")
#define LGKML asm volatile("s_waitcnt lgkmcnt(0)" ::: "memory")
#define VMNOP do {} while (0)

// -------- pure-gll16 tile (A,B both bf16 in global): GEMM1 --------
#define DO_TILE(ISS, VMA, VMB, VMD)                                           \
  do {                                                                        \
    short8 Af[4][2], Bf0[2][2], Bf1[2][2];                                    \
    _Pragma("unroll") for (int m = 0; m < 4; ++m) {                           \
      Af[m][0] = *(const short8*)(la + rpA[m] + sw0);                         \
      Af[m][1] = *(const short8*)(la + rpA[m] + sw1);                         \
    }                                                                         \
    _Pragma("unroll") for (int n = 0; n < 2; ++n) {                           \
      Bf0[n][0] = *(const short8*)(lb + rpB[n] + sw0);                        \
      Bf0[n][1] = *(const short8*)(lb + rpB[n] + sw1);                        \
    }                                                                         \
    if (ISS) { gll16(AG + (saO00 + knx), danext + ldst);                      \
               gll16(AG + (saO01 + knx), danext + 4096 + ldst); }             \
    SBAR(); LGKM0();                                                          \
    __builtin_amdgcn_s_setprio(1);                                            \
    _Pragma("unroll") for (int m = 0; m < 4; ++m)                             \
      _Pragma("unroll") for (int n = 0; n < 2; ++n) {                         \
        acc[m][n] = MFMA16(Af[m][0], Bf0[n][0], acc[m][n]);                   \
        acc[m][n] = MFMA16(Af[m][1], Bf0[n][1], acc[m][n]);                   \
      }                                                                       \
    __builtin_amdgcn_s_setprio(0); SCHED0(); VMA; SBAR();                     \
    _Pragma("unroll") for (int n = 0; n < 2; ++n) {                           \
      Bf1[n][0] = *(const short8*)(lb + rpB[n + 2] + sw0);                    \
      Bf1[n][1] = *(const short8*)(lb + rpB[n + 2] + sw1);                    \
    }                                                                         \
    if (ISS) { gll16(BG + (sbO00 + knx), dbnext + ldst);                      \
               gll16(BG + (sbO01 + knx), dbnext + 4096 + ldst); }             \
    SBAR(); LGKM0();                                                          \
    __builtin_amdgcn_s_setprio(1);                                            \
    _Pragma("unroll") for (int m = 0; m < 4; ++m)                             \
      _Pragma("unroll") for (int n = 0; n < 2; ++n) {                         \
        acc[m][n + 2] = MFMA16(Af[m][0], Bf1[n][0], acc[m][n + 2]);           \
        acc[m][n + 2] = MFMA16(Af[m][1], Bf1[n][1], acc[m][n + 2]);           \
      }                                                                       \
    __builtin_amdgcn_s_setprio(0); SCHED0(); VMB; SBAR();                     \
    _Pragma("unroll") for (int m = 0; m < 4; ++m) {                           \
      Af[m][0] = *(const short8*)(la + rpA[m + 4] + sw0);                     \
      Af[m][1] = *(const short8*)(la + rpA[m + 4] + sw1);                     \
    }                                                                         \
    if (ISS) { gll16(BG + (sbO10 + knx), dbnext + 8192 + ldst);               \
               gll16(BG + (sbO11 + knx), dbnext + 8192 + 4096 + ldst); }      \
    SBAR(); LGKM0();                                                          \
    __builtin_amdgcn_s_setprio(1);                                            \
    _Pragma("unroll") for (int m = 0; m < 4; ++m)                             \
      _Pragma("unroll") for (int n = 0; n < 2; ++n) {                         \
        acc[m + 4][n] = MFMA16(Af[m][0], Bf0[n][0], acc[m + 4][n]);           \
        acc[m + 4][n] = MFMA16(Af[m][1], Bf0[n][1], acc[m + 4][n]);           \
      }                                                                       \
    __builtin_amdgcn_s_setprio(0); SCHED0(); SBAR();                          \
    if (ISS) { gll16(AG + (saO10 + knx), danext + 8192 + ldst);               \
               gll16(AG + (saO11 + knx), danext + 8192 + 4096 + ldst); }      \
    __builtin_amdgcn_s_setprio(1);                                            \
    _Pragma("unroll") for (int m = 0; m < 4; ++m)                             \
      _Pragma("unroll") for (int n = 0; n < 2; ++n) {                         \
        acc[m + 4][n + 2] = MFMA16(Af[m][1], Bf1[n][1], acc[m + 4][n + 2]);   \
        acc[m + 4][n + 2] = MFMA16(Af[m][0], Bf1[n][0], acc[m + 4][n + 2]);   \
      }                                                                       \
    __builtin_amdgcn_s_setprio(0); SCHED0(); VMD; SBAR();                     \
  } while (0)

// -------- mixed tile (GEMM2): A bf16 via gll16 @ph0, B f32 reg ping-pong --------
// ph0: rd Ach0+Bch0 | issue 4 A gll16 (tile T+1)      | MFMA q0
// ph1: rd Bch1                                        | MFMA q1
// ph2: rd Ach1 | MFMA q2 | cvt_pk bn ch0/1 -> dbnext; reload bn (tile T+2)
// ph3:         | MFMA q3 | cvt_pk bn ch2/3 -> dbnext; reload bn | vmcnt(8)+lgkm0
#define DO_TILE2(ISS, KNXA, KNX2, WEND)                                       \
  do {                                                                        \
    short8 Af[4][2], Bf0[2][2], Bf1[2][2];                                    \
    _Pragma("unroll") for (int m = 0; m < 4; ++m) {                           \
      Af[m][0] = *(const short8*)(la + rpA[m] + sw0);                         \
      Af[m][1] = *(const short8*)(la + rpA[m] + sw1);                         \
    }                                                                         \
    _Pragma("unroll") for (int n = 0; n < 2; ++n) {                           \
      Bf0[n][0] = *(const short8*)(lb + rpB[n] + sw0);                        \
      Bf0[n][1] = *(const short8*)(lb + rpB[n] + sw1);                        \
    }                                                                         \
    if (ISS) {                                                                \
      gll16(AG + (saO00 + (KNXA)), danext + ldst);                            \
      gll16(AG + (saO01 + (KNXA)), danext + 4096 + ldst);                     \
      gll16(AG + (saO10 + (KNXA)), danext + 8192 + ldst);                     \
      gll16(AG + (saO11 + (KNXA)), danext + 8192 + 4096 + ldst);              \
    }                                                                         \
    SBAR(); LGKM0();                                                          \
    __builtin_amdgcn_s_setprio(1);                                            \
    _Pragma("unroll") for (int m = 0; m < 4; ++m)                             \
      _Pragma("unroll") for (int n = 0; n < 2; ++n) {                         \
        acc[m][n] = MFMA16(Af[m][0], Bf0[n][0], acc[m][n]);                   \
        acc[m][n] = MFMA16(Af[m][1], Bf0[n][1], acc[m][n]);                   \
      }                                                                       \
    __builtin_amdgcn_s_setprio(0); SCHED0(); SBAR();                          \
    _Pragma("unroll") for (int n = 0; n < 2; ++n) {                           \
      Bf1[n][0] = *(const short8*)(lb + rpB[n + 2] + sw0);                    \
      Bf1[n][1] = *(const short8*)(lb + rpB[n + 2] + sw1);                    \
    }                                                                         \
    SBAR(); LGKM0();                                                          \
    __builtin_amdgcn_s_setprio(1);                                            \
    _Pragma("unroll") for (int m = 0; m < 4; ++m)                             \
      _Pragma("unroll") for (int n = 0; n < 2; ++n) {                         \
        acc[m][n + 2] = MFMA16(Af[m][0], Bf1[n][0], acc[m][n + 2]);           \
        acc[m][n + 2] = MFMA16(Af[m][1], Bf1[n][1], acc[m][n + 2]);           \
      }                                                                       \
    __builtin_amdgcn_s_setprio(0); SCHED0(); SBAR();                          \
    _Pragma("unroll") for (int m = 0; m < 4; ++m) {                           \
      Af[m][0] = *(const short8*)(la + rpA[m + 4] + sw0);                     \
      Af[m][1] = *(const short8*)(la + rpA[m + 4] + sw1);                     \
    }                                                                         \
    SBAR(); LGKM0();                                                          \
    __builtin_amdgcn_s_setprio(1);                                            \
    _Pragma("unroll") for (int m = 0; m < 4; ++m)                             \
      _Pragma("unroll") for (int n = 0; n < 2; ++n) {                         \
        acc[m + 4][n] = MFMA16(Af[m][0], Bf0[n][0], acc[m + 4][n]);           \
        acc[m + 4][n] = MFMA16(Af[m][1], Bf0[n][1], acc[m + 4][n]);           \
      }                                                                       \
    __builtin_amdgcn_s_setprio(0);                                            \
    if (ISS) {                                                                \
      _Pragma("unroll") for (int c = 0; c < 2; ++c) {                         \
        u32x4 wv;                                                             \
        wv.x = cvtpk(bn[2 * c].x, bn[2 * c].y);                               \
        wv.y = cvtpk(bn[2 * c].z, bn[2 * c].w);                               \
        wv.z = cvtpk(bn[2 * c + 1].x, bn[2 * c + 1].y);                       \
        wv.w = cvtpk(bn[2 * c + 1].z, bn[2 * c + 1].w);                       \
        *(u32x4*)(dbnext + c * 4096 + (tid << 3)) = wv;                       \
        bn[2 * c]     = *(const f32x4*)(BGf + bro[c] + (KNX2) + swsrc);       \
        bn[2 * c + 1] = *(const f32x4*)(BGf + bro[c] + (KNX2) + swsrc + 4);   \
      }                                                                       \
    }                                                                         \
    SBAR();                                                                   \
    __builtin_amdgcn_s_setprio(1);                                            \
    _Pragma("unroll") for (int m = 0; m < 4; ++m)                             \
      _Pragma("unroll") for (int n = 0; n < 2; ++n) {                         \
        acc[m + 4][n + 2] = MFMA16(Af[m][0], Bf1[n][0], acc[m + 4][n + 2]);   \
        acc[m + 4][n + 2] = MFMA16(Af[m][1], Bf1[n][1], acc[m + 4][n + 2]);   \
      }                                                                       \
    __builtin_amdgcn_s_setprio(0);                                            \
    if (ISS) {                                                                \
      _Pragma("unroll") for (int c = 2; c < 4; ++c) {                         \
        u32x4 wv;                                                             \
        wv.x = cvtpk(bn[2 * c].x, bn[2 * c].y);                               \
        wv.y = cvtpk(bn[2 * c].z, bn[2 * c].w);                               \
        wv.z = cvtpk(bn[2 * c + 1].x, bn[2 * c + 1].y);                       \
        wv.w = cvtpk(bn[2 * c + 1].z, bn[2 * c + 1].w);                       \
        *(u32x4*)(dbnext + c * 4096 + (tid << 3)) = wv;                       \
        bn[2 * c]     = *(const f32x4*)(BGf + bro[c] + (KNX2) + swsrc);       \
        bn[2 * c + 1] = *(const f32x4*)(BGf + bro[c] + (KNX2) + swsrc + 4);   \
      }                                                                       \
    }                                                                         \
    WEND; SBAR();                                                             \
  } while (0)

// ================= GEMM1: wg = x_bf @ W1_bf^T + b1 (8-phase 256^2) =================
__global__ __launch_bounds__(512, 2) void k_gemm1_8ph(const u16* __restrict__ AG,
                                                      const u16* __restrict__ BG,
                                                      const float* __restrict__ bias,
                                                      u16* __restrict__ C,
                                                      float* __restrict__ wgn2) {
    __shared__ __align__(16) u16 LsA[2][16384];
    __shared__ __align__(16) u16 LsB[2][16384];
    const int K = 1024, NT = 16;
    const int lin = blockIdx.x;
    const int w = (lin & 7) * 32 + (lin >> 3);
    const int n0 = (w & 3) * 256;
    const int m0 = (w >> 2) * 256;

    const int tid = threadIdx.x, wave = tid >> 6, lane = tid & 63;
    const int lr = lane & 15, kq = lane >> 4;
    const int wr = wave >> 2, wc = wave & 3;

    const int trow = tid >> 3;
    const u32 swsrc = (u32)(((tid & 7) ^ (trow & 7)) * 8);
    const u32 saO00 = (u32)(m0 + 0 + trow) * (u32)K + swsrc;
    const u32 saO01 = (u32)(m0 + 128 + trow) * (u32)K + swsrc;
    const u32 saO10 = (u32)(m0 + 64 + trow) * (u32)K + swsrc;
    const u32 saO11 = (u32)(m0 + 192 + trow) * (u32)K + swsrc;
    const int q0 = trow, q1 = 64 + trow;
    const u32 sbO00 = (u32)(n0 + (q0 >> 5) * 64 + (q0 & 31)) * (u32)K + swsrc;
    const u32 sbO01 = (u32)(n0 + (q1 >> 5) * 64 + (q1 & 31)) * (u32)K + swsrc;
    const u32 sbO10 = (u32)(n0 + (q0 >> 5) * 64 + 32 + (q0 & 31)) * (u32)K + swsrc;
    const u32 sbO11 = (u32)(n0 + (q1 >> 5) * 64 + 32 + (q1 & 31)) * (u32)K + swsrc;
    const u32 ldst = (u32)wave * 512;

    int rpA[8], rpB[4];
#pragma unroll
    for (int mf = 0; mf < 8; ++mf)
        rpA[mf] = ((mf >> 2) * 128 + wr * 64 + (mf & 3) * 16 + lr) << 6;
#pragma unroll
    for (int nf = 0; nf < 4; ++nf)
        rpB[nf] = ((nf >> 1) * 128 + wc * 32 + (nf & 1) * 16 + lr) << 6;
    const int sw0 = ((0 + kq) ^ (lr & 7)) * 8;
    const int sw1 = ((4 + kq) ^ (lr & 7)) * 8;

    f32x4 acc[8][4] = {};

    gll16(AG + saO00, &LsA[0][0] + ldst);
    gll16(AG + saO01, &LsA[0][0] + 4096 + ldst);
    gll16(BG + sbO00, &LsB[0][0] + ldst);
    gll16(BG + sbO01, &LsB[0][0] + 4096 + ldst);
    gll16(BG + sbO10, &LsB[0][0] + 8192 + ldst);
    gll16(BG + sbO11, &LsB[0][0] + 8192 + 4096 + ldst);
    gll16(AG + saO10, &LsA[0][0] + 8192 + ldst);
    gll16(AG + saO11, &LsA[0][0] + 8192 + 4096 + ldst);
    VMW4;
    SBAR();

    int cur = 0;
    u32 ko = 64;
    for (int T = 0; T < NT - 1; ++T) {
        const u16* la = &LsA[cur][0];
        const u16* lb = &LsB[cur][0];
        u16* danext = &LsA[cur ^ 1][0];
        u16* dbnext = &LsB[cur ^ 1][0];
        const u32 knx = ko;
        DO_TILE(1, VMW4, VMW4, VMW4);
        cur ^= 1;
        ko += 64;
    }
    {
        const u16* la = &LsA[cur][0];
        const u16* lb = &LsB[cur][0];
        u16* danext = &LsA[cur ^ 1][0];
        u16* dbnext = &LsB[cur ^ 1][0];
        const u32 knx = 0;
        (void)danext; (void)dbnext;
        DO_TILE(0, VMW2, VMW0, VMNOP);
    }

    const int col0 = n0 + wc * 64;
    const int row0 = m0 + wr * 128;
    float bcol[4];
#pragma unroll
    for (int nf = 0; nf < 4; ++nf) bcol[nf] = bias[col0 + nf * 16 + lr];
#pragma unroll
    for (int mf = 0; mf < 8; ++mf) {
#pragma unroll
        for (int r = 0; r < 4; ++r) {
            const int row = row0 + mf * 16 + kq * 4 + r;
            float nrm = 0.f;
#pragma unroll
            for (int nf = 0; nf < 4; ++nf) {
                float v = acc[mf][nf][r] + bcol[nf];
                C[(size_t)row * 1024 + col0 + nf * 16 + lr] = f2bf(v);
                nrm += v * v;
            }
#pragma unroll
            for (int off = 1; off < 16; off <<= 1) nrm += __shfl_xor(nrm, off, 64);
            if (lr == 0) atomicAdd(&wgn2[row], nrm);
        }
    }
}

// ================= GEMM2: part[z] = attn_bf @ W_mlp^T (fused cvt, deep-prefetch 8-phase) ======
__global__ __launch_bounds__(512, 2) void k_gemm2_8ph(const u16* __restrict__ AG,
                                                      const float* __restrict__ BGf,
                                                      u16* __restrict__ part) {
    __shared__ __align__(16) u16 LsA[2][16384];
    __shared__ __align__(16) u16 LsB[2][16384];
    const int K = 16384, NT = 64;
    const int lin = blockIdx.x;
    const int w = (lin & 7) * 32 + (lin >> 3);
    const int m0 = (w & 3) * 256;
    const int z = (w >> 2) & 3;
    const int n0 = (w >> 4) * 256;
    const int kbeg = z * 4096;

    const int tid = threadIdx.x, wave = tid >> 6, lane = tid & 63;
    const int lr = lane & 15, kq = lane >> 4;
    const int wr = wave >> 2, wc = wave & 3;

    const int trow = tid >> 3;
    const u32 swsrc = (u32)(((tid & 7) ^ (trow & 7)) * 8);
    const u32 saO00 = (u32)(m0 + 0 + trow) * (u32)K + (u32)kbeg + swsrc;
    const u32 saO01 = (u32)(m0 + 128 + trow) * (u32)K + (u32)kbeg + swsrc;
    const u32 saO10 = (u32)(m0 + 64 + trow) * (u32)K + (u32)kbeg + swsrc;
    const u32 saO11 = (u32)(m0 + 192 + trow) * (u32)K + (u32)kbeg + swsrc;
    const int q0 = trow, q1 = 64 + trow;
    size_t bro[4];
    bro[0] = (size_t)(n0 + (q0 >> 5) * 64 + (q0 & 31)) * 16384 + kbeg;
    bro[1] = (size_t)(n0 + (q1 >> 5) * 64 + (q1 & 31)) * 16384 + kbeg;
    bro[2] = bro[0] + 32ull * 16384;
    bro[3] = bro[1] + 32ull * 16384;
    const u32 ldst = (u32)wave * 512;

    int rpA[8], rpB[4];
#pragma unroll
    for (int mf = 0; mf < 8; ++mf)
        rpA[mf] = ((mf >> 2) * 128 + wr * 64 + (mf & 3) * 16 + lr) << 6;
#pragma unroll
    for (int nf = 0; nf < 4; ++nf)
        rpB[nf] = ((nf >> 1) * 128 + wc * 32 + (nf & 1) * 16 + lr) << 6;
    const int sw0 = ((0 + kq) ^ (lr & 7)) * 8;
    const int sw1 = ((4 + kq) ^ (lr & 7)) * 8;

    f32x4 acc[8][4] = {};
    f32x4 bn[8];

    // prologue: tile0 B load+cvt into LsB[0], A via gll16; then preload bn for tile1
    {
#pragma unroll
        for (int c = 0; c < 4; ++c) {
            bn[2 * c]     = *(const f32x4*)(BGf + bro[c] + swsrc);
            bn[2 * c + 1] = *(const f32x4*)(BGf + bro[c] + swsrc + 4);
        }
        gll16(AG + saO00, &LsA[0][0] + ldst);
        gll16(AG + saO01, &LsA[0][0] + 4096 + ldst);
        gll16(AG + saO10, &LsA[0][0] + 8192 + ldst);
        gll16(AG + saO11, &LsA[0][0] + 8192 + 4096 + ldst);
#pragma unroll
        for (int c = 0; c < 4; ++c) {
            u32x4 wv;
            wv.x = cvtpk(bn[2 * c].x, bn[2 * c].y);
            wv.y = cvtpk(bn[2 * c].z, bn[2 * c].w);
            wv.z = cvtpk(bn[2 * c + 1].x, bn[2 * c + 1].y);
            wv.w = cvtpk(bn[2 * c + 1].z, bn[2 * c + 1].w);
            *(u32x4*)(&LsB[0][0] + c * 4096 + (tid << 3)) = wv;
        }
        asm volatile("s_waitcnt vmcnt(0) lgkmcnt(0)" ::: "memory");
        // preload bn regs for tile 1 (stay outstanding across the barrier)
#pragma unroll
        for (int c = 0; c < 4; ++c) {
            bn[2 * c]     = *(const f32x4*)(BGf + bro[c] + 64 + swsrc);
            bn[2 * c + 1] = *(const f32x4*)(BGf + bro[c] + 64 + swsrc + 4);
        }
        SBAR();
    }

    int cur = 0;
    for (int T = 0; T < NT - 1; ++T) {
        const u16* la = &LsA[cur][0];
        const u16* lb = &LsB[cur][0];
        u16* danext = &LsA[cur ^ 1][0];
        u16* dbnext = &LsB[cur ^ 1][0];
        const u32 knxa = (u32)(T + 1) * 64;
        const u32 knx2 = (T + 2 < NT) ? (u32)(T + 2) * 64 : 0u;
        DO_TILE2(1, knxa, knx2, VMW8L);
        cur ^= 1;
    }
    {
        const u16* la = &LsA[cur][0];
        const u16* lb = &LsB[cur][0];
        u16* danext = &LsA[cur ^ 1][0];
        u16* dbnext = &LsB[cur ^ 1][0];
        (void)danext; (void)dbnext;
        DO_TILE2(0, 0u, 0u, VMNOP);
    }

    u16* po = part + (size_t)z * 4194304ull;
    const int col0 = n0 + wc * 64;
    const int row0 = m0 + wr * 128;
#pragma unroll
    for (int mf = 0; mf < 8; ++mf)
#pragma unroll
        for (int r = 0; r < 4; ++r) {
            const int row = row0 + mf * 16 + kq * 4 + r;
#pragma unroll
            for (int nf = 0; nf < 4; ++nf)
                po[(size_t)row * 4096 + col0 + nf * 16 + lr] = f2bf(acc[mf][nf][r]);
        }
}

// ---------- per-batch graph algebra ----------
__global__ __launch_bounds__(64) void k_batch(const u16* __restrict__ xb,
                                              const u16* __restrict__ wgb,
                                              const float* __restrict__ xinv,
                                              const float* __restrict__ wgn2,
                                              const float* __restrict__ matrix,
                                              const float* __restrict__ a_param,
                                              float* __restrict__ ascores,
                                              float* __restrict__ e2_out,
                                              float* __restrict__ m_out) {
    const int b = blockIdx.x, l = threadIdx.x;
    const int j = l & 15, ig = (l >> 4) * 4;
    const size_t roff = (size_t)(b * 16 + j) * 1024 + (l >> 4) * 8;
    f32x4 acc0 = {}, acc1 = {};
#pragma unroll
    for (int kt = 0; kt < 1024; kt += 64) {
        short8 xa0 = *(const short8*)(xb + roff + kt);
        short8 wa0 = *(const short8*)(wgb + roff + kt);
        short8 xa1 = *(const short8*)(xb + roff + kt + 32);
        short8 wa1 = *(const short8*)(wgb + roff + kt + 32);
        acc0 = __builtin_amdgcn_mfma_f32_16x16x32_bf16(xa0, wa0, acc0, 0, 0, 0);
        acc1 = __builtin_amdgcn_mfma_f32_16x16x32_bf16(xa1, wa1, acc1, 0, 0, 0);
    }
    const float inw = 1.0f / fmaxf(sqrtf(wgn2[b * 16 + j]), 1e-12f);
    const float boost = 1.0f + a_param[0];
    float e[4];
#pragma unroll
    for (int r = 0; r < 4; ++r) {
        const int i = ig + r;
        float v = (acc0[r] + acc1[r]) * xinv[b * 16 + i] * inw;
        if (i == j) v *= boost;
        e[r] = v;
        ascores[(size_t)b * 256 + i * 16 + j] = v;
    }
    float mx = fmaxf(fmaxf(e[0], e[1]), fmaxf(e[2], e[3]));
    mx = fmaxf(mx, __shfl_xor(mx, 16, 64));
    mx = fmaxf(mx, __shfl_xor(mx, 32, 64));
    float p[4], s = 0.f;
#pragma unroll
    for (int r = 0; r < 4; ++r) { p[r] = __expf(e[r] - mx); s += p[r]; }
    s += __shfl_xor(s, 16, 64);
    s += __shfl_xor(s, 32, 64);
    const float invs = 1.0f / s;

    __shared__ float esm_l[16 * 17];
    __shared__ float fi_l[16 * 17];
    __shared__ float e2_l[16 * 17];
    __shared__ float m_l[256];
#pragma unroll
    for (int r = 0; r < 4; ++r) esm_l[(ig + r) * 17 + j] = p[r] * invs;
    const f32x4 mv = *(const f32x4*)(matrix + (size_t)b * 256 + 4 * l);
    *(f32x4*)(m_l + 4 * l) = mv;
    *(f32x4*)(m_out + (size_t)b * 256 + 4 * l) = mv;
    __syncthreads();
    float fi[4] = {0, 0, 0, 0};
#pragma unroll
    for (int t = 0; t < 16; ++t) {
        const float mk = m_l[t * 16 + j];
#pragma unroll
        for (int r = 0; r < 4; ++r) fi[r] += esm_l[(ig + r) * 17 + t] * mk;
    }
#pragma unroll
    for (int r = 0; r < 4; ++r) fi_l[(ig + r) * 17 + j] = fi[r];
    __syncthreads();
    float e2v[4] = {0, 0, 0, 0};
#pragma unroll
    for (int kk = 0; kk < 16; ++kk) {
        const float wgt = esm_l[j * 17 + kk] * m_l[kk * 16 + kk];
#pragma unroll
        for (int r = 0; r < 4; ++r) e2v[r] += fi_l[(ig + r) * 17 + kk] * wgt;
    }
#pragma unroll
    for (int r = 0; r < 4; ++r) e2_l[(ig + r) * 17 + j] = e2v[r];
    __syncthreads();
#pragma unroll
    for (int r = 0; r < 4; ++r) {
        const int i = ig + r;
        e2_out[(size_t)b * 256 + i * 16 + j] = 0.5f * (e2_l[i * 17 + j] + e2_l[j * 17 + i]);
    }
}

// ---------- attn[b,i,f] = tanh(sum_j ascores[b,j,i] * x[b,j,f]) -> bf16 ----------
__global__ __launch_bounds__(256) void k_attn(const float* __restrict__ x,
                                              const float* __restrict__ ascores,
                                              u16* __restrict__ attn_bf) {
    __shared__ float xl[16][256];
    __shared__ float as_l[256];
    const int b = blockIdx.y, f0 = blockIdx.x * 256, t = threadIdx.x;
    as_l[t] = ascores[(size_t)b * 256 + t];
#pragma unroll
    for (int jj = 0; jj < 16; ++jj)
        xl[jj][t] = x[((size_t)b * 16 + jj) * 1024 + f0 + t];
    __syncthreads();
    float accv[16] = {};
#pragma unroll
    for (int jj = 0; jj < 16; ++jj) {
        const float xv = xl[jj][t];
#pragma unroll
        for (int i = 0; i < 16; ++i) accv[i] = fmaf(as_l[jj * 16 + i], xv, accv[i]);
    }
#pragma unroll
    for (int i = 0; i < 16; ++i)
        attn_bf[((size_t)b * 16 + i) * 1024 + f0 + t] = f2bf(tanhf(accv[i]));
}

// ---------- broadcast: out[b, rep, :] = sum_z part[z][b,:] + b_mlp ----------
__global__ __launch_bounds__(256) void k_bcast(const u16* __restrict__ p,
                                               const float* __restrict__ bias,
                                               float* __restrict__ out) {
    const size_t i = (size_t)blockIdx.x * 256 + threadIdx.x;
    const int o4 = (int)(i & 1023);
    const int b = (int)(i >> 14);
    const size_t src = (size_t)b * 4096 + (size_t)o4 * 4;
    f32x4 r = *(const f32x4*)(bias + (size_t)o4 * 4);
#pragma unroll
    for (int z = 0; z < 4; ++z) {
        us4 v = *(const us4*)(p + (size_t)z * 4194304ull + src);
        r.x += bf2f(v.x); r.y += bf2f(v.y); r.z += bf2f(v.z); r.w += bf2f(v.w);
    }
    *(f32x4*)(out + i * 4) = r;
}

extern "C" void kernel_launch(void* const* d_in, const int* in_sizes, int n_in,
                              void* d_out, int out_size, void* d_ws, size_t ws_size,
                              hipStream_t stream) {
    const float* x      = (const float*)d_in[0];
    const float* matrix = (const float*)d_in[1];
    const float* W1     = (const float*)d_in[2];
    const float* b1     = (const float*)d_in[3];
    const float* W_mlp  = (const float*)d_in[4];
    const float* b_mlp  = (const float*)d_in[5];
    const float* a_par  = (const float*)d_in[6];
    float* out = (float*)d_out;

    char* ws = (char*)d_ws;
    size_t off = 0;
    auto alloc = [&](size_t bytes) {
        char* p = ws + off;
        off += (bytes + 255) & ~(size_t)255;
        return p;
    };
    u16*   x_bf  = (u16*)alloc(16384ull * 1024 * 2);    // reused as attn_bf after k_batch
    u16*   wg_bf = (u16*)alloc(16384ull * 1024 * 2);    // reused as GEMM2 bf16 partials (4 x 8MB)
    u16*   w1_bf = (u16*)alloc(1024ull * 1024 * 2);
    float* xinv  = (float*)alloc(16384ull * 4);
    float* wgn2  = (float*)alloc(16384ull * 4);
    float* ascr  = (float*)alloc(1024ull * 256 * 4);
    u16*   attn_bf = x_bf;
    u16*   part    = wg_bf;
    float* e2_out = out + 67108864ull;
    float* m_out  = out + 67371008ull;

    hipMemsetAsync(wgn2, 0, 16384 * 4, stream);
    k_cvt_x<<<16384, 256, 0, stream>>>(x, x_bf, xinv);
    k_cvt<<<1024, 256, 0, stream>>>(W1, w1_bf);
    k_gemm1_8ph<<<256, 512, 0, stream>>>(x_bf, w1_bf, b1, wg_bf, wgn2);
    k_batch<<<1024, 64, 0, stream>>>(x_bf, wg_bf, xinv, wgn2, matrix, a_par,
                                     ascr, e2_out, m_out);
    k_attn<<<dim3(4, 1024), 256, 0, stream>>>(x, ascr, attn_bf);
    k_gemm2_8ph<<<256, 512, 0, stream>>>(attn_bf, W_mlp, part);
    k_bcast<<<65536, 256, 0, stream>>>(part, b_mlp, out);
}